// Round 16
// baseline (213.704 us; speedup 1.0000x reference)
//
#include <hip/hip_runtime.h>
#include <math.h>

// ---------------- types & helpers ----------------
typedef float f32x4 __attribute__((ext_vector_type(4)));
typedef short s16x8 __attribute__((ext_vector_type(8)));

#define DEV static __device__ __forceinline__

DEV float wsum(float v){
  #pragma unroll
  for(int m=1;m<64;m<<=1) v += __shfl_xor(v,m);
  return v;
}
template<int NW>
DEV float bsum(float v, float* s){
  v = wsum(v);
  int w = threadIdx.x>>6;
  if((threadIdx.x&63)==0) s[w]=v;
  __syncthreads();
  float r = 0.f;
  #pragma unroll
  for(int i=0;i<NW;++i) r += s[i];
  __syncthreads();
  return r;
}
DEV float xexp2(float x){
#if __has_builtin(__builtin_amdgcn_exp2f)
  return __builtin_amdgcn_exp2f(x);
#else
  return exp2f(x);
#endif
}
DEV unsigned pkbf(float lo, float hi){
  unsigned r;
  asm("v_cvt_pk_bf16_f32 %0, %1, %2" : "=v"(r) : "v"(lo), "v"(hi));
  return r;
}
DEV unsigned short bf16c(float v){ return (unsigned short)(pkbf(v, 0.f) & 0xffffu); }
DEV float ubf_lo(unsigned u){ unsigned b=(u&0xffffu)<<16; return __builtin_bit_cast(float,b); }
DEV float ubf_hi(unsigned u){ unsigned b=(u>>16)<<16;    return __builtin_bit_cast(float,b); }
union FR { unsigned u[4]; s16x8 v; uint4 q; };

DEV f32x4 MF(s16x8 a, s16x8 b, f32x4 c){
  return __builtin_amdgcn_mfma_f32_16x16x32_bf16(a, b, c, 0,0,0);
}

// async global -> LDS, 16B per lane; dest = wave-uniform base + lane*16
DEV void gl_lds16(const void* g, void* l){
  __builtin_amdgcn_global_load_lds(
    (const __attribute__((address_space(1))) void*)g,
    (__attribute__((address_space(3))) void*)l, 16, 0, 0);
}

// ---------------- projection + bilinear sample -> vfeat [B,N,64] ----------------
__global__ __launch_bounds__(256) void k_proj(const float* __restrict__ gs, const float* __restrict__ vf,
                       const float* __restrict__ E, const float* __restrict__ Kin,
                       const float* __restrict__ off, float* __restrict__ vfeat){
  int bn = blockIdx.x*4 + (threadIdx.x>>6); int b = bn>>11; int c = threadIdx.x&63;
  const float* g = gs + (size_t)bn*14;
  float px = g[0], py = g[1], pz = g[2];
  float ox = off[bn*2+0], oy = off[bn*2+1];
  float acc = 0.f, vsum = 0.f;
  for(int v=0; v<4; ++v){
    const float* e = E + ((b*4+v)*16);
    float cx = e[0]*px + e[1]*py + e[2]*pz + e[3];
    float cy = e[4]*px + e[5]*py + e[6]*pz + e[7];
    float cz = e[8]*px + e[9]*py + e[10]*pz + e[11];
    const float* kk = Kin + ((b*4+v)*9);
    float ux = kk[0]*cx + kk[1]*cy + kk[2]*cz;
    float uy = kk[3]*cx + kk[4]*cy + kk[5]*cz;
    float uz = kk[6]*cx + kk[7]*cy + kk[8]*cz;
    float dep = fmaxf(uz, 1e-6f);
    float gx = 2.f*(ux/dep)*(1.f/448.f) - 1.f + ox;
    float gy = 2.f*(uy/dep)*(1.f/448.f) - 1.f + oy;
    float valid = (uz > 0.1f && gx >= -1.f && gx <= 1.f && gy >= -1.f && gy <= 1.f) ? 1.f : 0.f;
    float x = (gx+1.f)*16.f - 0.5f;
    float y = (gy+1.f)*16.f - 0.5f;
    float x0 = floorf(x), y0 = floorf(y);
    const float* fbase = vf + (size_t)((b*4+v)*64 + c)*1024;
    float sv = 0.f;
    #pragma unroll
    for(int t=0;t<4;++t){
      float xi = x0 + (float)(t&1), yi = y0 + (float)(t>>1);
      float wgt = (1.f - fabsf(x-xi))*(1.f - fabsf(y-yi));
      bool vt = (xi>=0.f && xi<32.f && yi>=0.f && yi<32.f);
      int xc = (int)fminf(fmaxf(xi,0.f),31.f);
      int yc = (int)fminf(fmaxf(yi,0.f),31.f);
      float smp = fbase[yc*32+xc];
      sv += vt ? wgt*smp : 0.f;
    }
    acc += valid * sv;
    vsum += valid;
  }
  vfeat[(size_t)bn*64 + c] = acc / (vsum + 1e-8f);
}

// ---------------- embed: g_emb / v_emb = relu(LN(x@W^T+b)) + bf16 copies ----------------
__global__ void k_embed(const float* __restrict__ gs, const float* __restrict__ vfeat,
   const float* __restrict__ pg_w, const float* __restrict__ pg_b,
   const float* __restrict__ pg_g, const float* __restrict__ pg_bb,
   const float* __restrict__ pv_w, const float* __restrict__ pv_b,
   const float* __restrict__ pv_g, const float* __restrict__ pv_bb,
   float* __restrict__ gemb, float* __restrict__ vemb,
   unsigned short* __restrict__ gembb, unsigned short* __restrict__ vembb){
  __shared__ float xs[64]; __shared__ float gsr[14]; __shared__ float red[2];
  int row = blockIdx.x; int d = threadIdx.x;
  if(d<14) gsr[d] = gs[(size_t)row*14+d];
  if(d<64) xs[d] = vfeat[(size_t)row*64+d];
  __syncthreads();
  float a = pg_b[d];
  #pragma unroll
  for(int j=0;j<14;++j) a += gsr[j]*pg_w[d*14+j];
  float mu = bsum<2>(a, red)*(1.f/128.f);
  float df = a-mu;
  float var = bsum<2>(df*df, red)*(1.f/128.f);
  float y = fmaxf(df*rsqrtf(var+1e-5f)*pg_g[d] + pg_bb[d], 0.f);
  gemb[(size_t)row*128+d] = y;
  gembb[(size_t)row*128+d] = bf16c(y);
  float av = pv_b[d];
  #pragma unroll
  for(int j=0;j<64;++j) av += xs[j]*pv_w[d*64+j];
  mu = bsum<2>(av, red)*(1.f/128.f);
  df = av-mu;
  var = bsum<2>(df*df, red)*(1.f/128.f);
  y = fmaxf(df*rsqrtf(var+1e-5f)*pv_g[d] + pv_bb[d], 0.f);
  vemb[(size_t)row*128+d] = y;
  vembb[(size_t)row*128+d] = bf16c(y);
}

// ---------------- weights -> bf16 (ipw | ow | gate_w | cw) ----------------
__global__ void k_wprep(const float* __restrict__ ipw, const float* __restrict__ ow,
                        const float* __restrict__ gw, const float* __restrict__ cw,
                        unsigned short* __restrict__ WB){
  int i = blockIdx.x*256 + threadIdx.x;   // 188416
  if(i >= 188416) return;
  float v;
  if(i < 98304)       v = ipw[i];
  else if(i < 131072) v = ow[i-98304];
  else if(i < 163840) v = gw[i-131072];
  else                v = cw[i-163840];
  WB[i] = bf16c(v);
}

// ---------------- fused QKV projection -> flash layout (bf16) ----------------
__global__ __launch_bounds__(256) void k_qkv(const unsigned short* __restrict__ GEb,
    const unsigned short* __restrict__ VEb, const unsigned short* __restrict__ WB,
    const float* __restrict__ ipb, unsigned* __restrict__ QKVu, float qsc){
  int mt = blockIdx.x, y = blockIdx.y;
  int m = y/6, j6 = y%6, kind = j6>>1, n0 = (j6&1)*64;
  const unsigned short* A = (kind==0) ? (m?VEb:GEb) : (m?GEb:VEb);
  const unsigned short* W = WB + m*49152 + kind*16384;
  const float* bias = ipb + m*384 + kind*128;
  unsigned* outb = QKVu + (size_t)m*1572864 + (size_t)kind*524288;
  float scale = (kind==0)? qsc : 1.f;
  int m0 = mt*64;
  int wid=threadIdx.x>>6, lane=threadIdx.x&63, lr=lane&15, lg=lane>>4;
  const unsigned short* ap = A + (size_t)(m0+wid*16+lr)*128 + lg*8;
  f32x4 acc[4] = {{0,0,0,0},{0,0,0,0},{0,0,0,0},{0,0,0,0}};
  #pragma unroll
  for(int ks=0; ks<128; ks+=32){
    FR af; af.v = *(const s16x8*)(ap + ks);
    #pragma unroll
    for(int nt=0; nt<4; ++nt){
      FR bf; bf.v = *(const s16x8*)(W + (size_t)(n0+nt*16+lr)*128 + ks + lg*8);
      acc[nt] = MF(af.v, bf.v, acc[nt]);
    }
  }
  __shared__ float xs[64][65];
  #pragma unroll
  for(int nt=0; nt<4; ++nt){
    float bv = bias[n0+nt*16+lr];
    #pragma unroll
    for(int r=0;r<4;++r) xs[wid*16+lg*4+r][nt*16+lr] = (acc[nt][r]+bv)*scale;
  }
  __syncthreads();
  if(kind<2){
    int i = threadIdx.x>>2, s = threadIdx.x&3;
    int gr = m0 + i, b = gr>>11, nn = gr&2047;
    int j0 = n0 + s*16, h = j0>>5, d0 = j0&31;
    unsigned w[8];
    #pragma unroll
    for(int p=0;p<8;++p) w[p] = pkbf(xs[i][s*16+2*p], xs[i][s*16+2*p+1]);
    unsigned* dst = outb + ((size_t)(b*4+h)*2048+nn)*16 + (d0>>1);
    uint4 u0; u0.x=w[0];u0.y=w[1];u0.z=w[2];u0.w=w[3];
    uint4 u1; u1.x=w[4];u1.y=w[5];u1.z=w[6];u1.w=w[7];
    *(uint4*)dst = u0; *(uint4*)(dst+4) = u1;
  } else {
    int c = threadIdx.x>>2, rs = threadIdx.x&3;
    int j = n0 + c, h = j>>5, d = j&31;
    int b = m0>>11, nn0 = m0&2047;
    unsigned w[8];
    #pragma unroll
    for(int p=0;p<8;++p) w[p] = pkbf(xs[rs*16+2*p][c], xs[rs*16+2*p+1][c]);
    unsigned* dst = outb + (size_t)(b*4+h)*32768 + (size_t)d*1024 + ((nn0+rs*16)>>1);
    uint4 u0; u0.x=w[0];u0.y=w[1];u0.z=w[2];u0.w=w[3];
    uint4 u1; u1.x=w[4];u1.y=w[5];u1.z=w[6];u1.w=w[7];
    *(uint4*)dst = u0; *(uint4*)(dst+4) = u1;
  }
}

// ---------------- MFMA bf16 flash attention v9 (r13/r15 best): LDS staging, K+V XOR-swizzled ----------------
__global__ __launch_bounds__(256) void k_flash(const unsigned short* __restrict__ QKV,
    unsigned* __restrict__ OPARTw, float* __restrict__ LSUM){
  int qt = blockIdx.x, h = blockIdx.y, z = blockIdx.z;   // grid (32,4,16)
  int mb = z&7, split = z>>3;
  int m = mb>>2, b = mb&3;
  const unsigned short* base = QKV + (size_t)m*3145728;
  const unsigned short* qp = base + (size_t)(b*4+h)*65536;
  const unsigned short* kp = qp + 1048576;
  const unsigned short* vp = qp + 2097152;
  int tid=threadIdx.x, wid=tid>>6, lane=tid&63, lr=lane&15, lg=lane>>4;
  __shared__ unsigned short KT[2][2048];
  __shared__ unsigned short VT[2][2048];
  __shared__ unsigned Ps[4][16][33];
  int q0 = qt*64 + wid*16;
  int kbase = split*1024;
  FR qf; qf.v = *(const s16x8*)(qp + (size_t)(q0+lr)*32 + lg*8);
  const f32x4 zz = {0.f,0.f,0.f,0.f};
  f32x4 o0g = zz, o1g = zz;
  float lrun = 0.f;
  unsigned* prow = &Ps[wid][lr][0];
  int kr = wid*16 + (lane>>2);
  int kscol = (((lane&3)<<3) ^ (((lane>>3)&3)<<3));
  const unsigned short* ksrc0 = kp + (size_t)(kbase + kr)*32 + kscol;
  int vrow = wid*8 + (lane>>3);
  int vscol = 8*((lane&7) ^ (lane>>3));
  const unsigned short* vsrc0 = vp + (size_t)vrow*2048 + kbase + vscol;
  int kkey = ((lr>>1)&3)<<3;
  int ko = lr*32 + ((lg*8) ^ kkey);
  int sw = (lr&7)*8;
  int vo0 = lr*64 + ((lg*8) ^ sw);
  int vo2 = lr*64 + ((32+lg*8) ^ sw);
  gl_lds16(ksrc0, &KT[0][wid*512]);
  gl_lds16(vsrc0, &VT[0][wid*512]);
  __syncthreads();
  int buf = 0;
  for(int t=0; t<16; ++t){
    int tn = (t+1)&15;
    gl_lds16(ksrc0 + (size_t)tn*2048, &KT[buf^1][wid*512]);
    gl_lds16(vsrc0 + tn*64,           &VT[buf^1][wid*512]);
    const unsigned short* Ktb = &KT[buf][0];
    const unsigned short* Vtb = &VT[buf][0];
    FR k0,k1,k2,k3;
    k0.v = *(const s16x8*)(Ktb + ko);
    k1.v = *(const s16x8*)(Ktb +  512 + ko);
    k2.v = *(const s16x8*)(Ktb + 1024 + ko);
    k3.v = *(const s16x8*)(Ktb + 1536 + ko);
    f32x4 s0 = MF(k0.v, qf.v, zz);
    f32x4 s1 = MF(k1.v, qf.v, zz);
    f32x4 s2 = MF(k2.v, qf.v, zz);
    f32x4 s3 = MF(k3.v, qf.v, zz);
    float p0[4],p1[4],p2[4],p3[4]; float ps=0.f;
    #pragma unroll
    for(int r=0;r<4;++r){
      p0[r]=xexp2(s0[r]); p1[r]=xexp2(s1[r]);
      p2[r]=xexp2(s2[r]); p3[r]=xexp2(s3[r]);
      ps += p0[r]+p1[r]+p2[r]+p3[r];
    }
    lrun += ps;
    asm volatile("" ::: "memory");
    prow[   lg*2+0]=pkbf(p0[0],p0[1]); prow[   lg*2+1]=pkbf(p0[2],p0[3]);
    prow[ 8+lg*2+0]=pkbf(p1[0],p1[1]); prow[ 8+lg*2+1]=pkbf(p1[2],p1[3]);
    prow[16+lg*2+0]=pkbf(p2[0],p2[1]); prow[16+lg*2+1]=pkbf(p2[2],p2[3]);
    prow[24+lg*2+0]=pkbf(p3[0],p3[1]); prow[24+lg*2+1]=pkbf(p3[2],p3[3]);
    asm volatile("" ::: "memory");
    FR pf0, pf1;
    #pragma unroll
    for(int i=0;i<4;++i){ pf0.u[i]=prow[lg*4+i]; pf1.u[i]=prow[16+lg*4+i]; }
    FR v0,v1,v2,v3;
    v0.v = *(const s16x8*)(Vtb + vo0);
    v1.v = *(const s16x8*)(Vtb + 1024 + vo0);
    v2.v = *(const s16x8*)(Vtb + vo2);
    v3.v = *(const s16x8*)(Vtb + 1024 + vo2);
    o0g = MF(v0.v, pf0.v, o0g);
    o1g = MF(v1.v, pf0.v, o1g);
    o0g = MF(v2.v, pf1.v, o0g);
    o1g = MF(v3.v, pf1.v, o1g);
    __syncthreads();
    buf ^= 1;
  }
  lrun += __shfl_xor(lrun,16); lrun += __shfl_xor(lrun,32);
  unsigned w00=pkbf(o0g[0],o0g[1]), w01=pkbf(o0g[2],o0g[3]);
  unsigned w10=pkbf(o1g[0],o1g[1]), w11=pkbf(o1g[2],o1g[3]);
  unsigned* op = OPARTw + ((size_t)(split*2+m)*8192 + (size_t)(b*2048+q0+lr))*64 + h*16 + lg*2;
  op[0]=w00; op[1]=w01; op[8]=w10; op[9]=w11;
  if(lg==0) LSUM[((size_t)(split*2+m)*16 + b*4+h)*2048 + q0+lr] = lrun;
}

// ---------------- fused split-K merge + out-proj GEMM + bias + residual + LN ----------------
__global__ __launch_bounds__(256) void k_oproj(const unsigned* __restrict__ OPARTw,
    const float* __restrict__ LSUM,
    const unsigned short* __restrict__ WB, const float* __restrict__ ob,
    const float* __restrict__ GE, const float* __restrict__ VE,
    const float* __restrict__ dg, const float* __restrict__ db,
    float* __restrict__ CC, unsigned short* __restrict__ CCb){
  int mt = blockIdx.x, m = blockIdx.y;
  int m0 = mt*64;
  const unsigned short* W = WB + 98304 + m*16384;
  const float* bias = ob + m*128;
  const float* R = m ? VE : GE;
  const float* gamma = dg + m*128;
  const float* beta  = db + m*128;
  int wid=threadIdx.x>>6, lane=threadIdx.x&63, lr=lane&15, lg=lane>>4;
  int gr = m0 + wid*16 + lr;
  int b2 = gr>>11, nn = gr&2047;
  float invh[4];
  #pragma unroll
  for(int h=0;h<4;++h){
    float l0 = LSUM[((size_t)(m*16) + b2*4+h)*2048 + nn];
    float l1 = LSUM[((size_t)((2+m)*16) + b2*4+h)*2048 + nn];
    invh[h] = 1.f/(l0+l1);
  }
  const unsigned* a0 = OPARTw + ((size_t)m*8192 + gr)*64 + lg*4;
  const unsigned* a1 = OPARTw + ((size_t)(2+m)*8192 + gr)*64 + lg*4;
  f32x4 acc[8] = {};
  #pragma unroll
  for(int ks=0; ks<4; ++ks){
    uint4 u0 = *(const uint4*)(a0 + ks*16);
    uint4 u1 = *(const uint4*)(a1 + ks*16);
    float sc = invh[ks];
    FR af;
    af.u[0] = pkbf((ubf_lo(u0.x)+ubf_lo(u1.x))*sc, (ubf_hi(u0.x)+ubf_hi(u1.x))*sc);
    af.u[1] = pkbf((ubf_lo(u0.y)+ubf_lo(u1.y))*sc, (ubf_hi(u0.y)+ubf_hi(u1.y))*sc);
    af.u[2] = pkbf((ubf_lo(u0.z)+ubf_lo(u1.z))*sc, (ubf_hi(u0.z)+ubf_hi(u1.z))*sc);
    af.u[3] = pkbf((ubf_lo(u0.w)+ubf_lo(u1.w))*sc, (ubf_hi(u0.w)+ubf_hi(u1.w))*sc);
    #pragma unroll
    for(int nt=0; nt<8; ++nt){
      FR bf; bf.v = *(const s16x8*)(W + (size_t)(nt*16+lr)*128 + ks*32 + lg*8);
      acc[nt] = MF(af.v, bf.v, acc[nt]);
    }
  }
  __shared__ float xs[64][129];
  __shared__ float mus[64], rss[64];
  #pragma unroll
  for(int nt=0; nt<8; ++nt){
    float bv = bias[nt*16+lr];
    #pragma unroll
    for(int r=0;r<4;++r){
      int row = wid*16+lg*4+r;
      xs[row][nt*16+lr] = acc[nt][r] + bv + R[(size_t)(m0+row)*128 + nt*16+lr];
    }
  }
  __syncthreads();
  if(threadIdx.x < 64){
    int row = threadIdx.x;
    float s=0.f, s2=0.f;
    #pragma unroll 8
    for(int c=0;c<128;++c){ float x = xs[row][c]; s += x; s2 += x*x; }
    float mu = s*(1.f/128.f);
    float var = fmaxf(s2*(1.f/128.f) - mu*mu, 0.f);
    mus[row] = mu; rss[row] = rsqrtf(var + 1e-5f);
  }
  __syncthreads();
  int row = threadIdx.x>>2, cs = (threadIdx.x&3)*32;
  float mu = mus[row], rs = rss[row];
  size_t obase = (size_t)(m0+row)*256 + m*128;
  #pragma unroll 8
  for(int c=cs;c<cs+32;++c){
    float y = (xs[row][c]-mu)*rs*gamma[c] + beta[c];
    CC [obase + c] = y;
    CCb[obase + c] = bf16c(y);
  }
}

// ---------------- fused gate GEMM + sigmoid + mix -> FU (grid (128,2)) ----------------
__global__ __launch_bounds__(256) void k_gatef(const unsigned short* __restrict__ CCb,
    const unsigned short* __restrict__ WB, const float* __restrict__ gate_b,
    const float* __restrict__ CC, float* __restrict__ FU){
  int mt = blockIdx.x, nh = blockIdx.y;
  int m0 = mt*64, c0 = nh*64;
  const unsigned short* W = WB + 131072;
  int wid=threadIdx.x>>6, lane=threadIdx.x&63, lr=lane&15, lg=lane>>4;
  const unsigned short* ap = CCb + (size_t)(m0+wid*16+lr)*256 + lg*8;
  f32x4 acc[4] = {};
  #pragma unroll
  for(int ks=0; ks<256; ks+=32){
    FR af; af.v = *(const s16x8*)(ap + ks);
    #pragma unroll
    for(int nt=0; nt<4; ++nt){
      FR bf; bf.v = *(const s16x8*)(W + (size_t)(c0+nt*16+lr)*256 + ks + lg*8);
      acc[nt] = MF(af.v, bf.v, acc[nt]);
    }
  }
  #pragma unroll
  for(int nt=0; nt<4; ++nt){
    int col = c0 + nt*16+lr;
    float bv = gate_b[col];
    #pragma unroll
    for(int r=0;r<4;++r){
      int row = m0 + wid*16+lg*4+r;
      float gv = 1.f/(1.f+__expf(-(acc[nt][r]+bv)));
      FU[(size_t)row*128 + col] = CC[(size_t)row*256 + col]*gv
                                + CC[(size_t)row*256 + 128 + col]*(1.f-gv);
    }
  }
}

// ---------------- router ----------------
__global__ __launch_bounds__(256) void k_rpart(const float* __restrict__ gemb, const float* __restrict__ vemb,
                        float* __restrict__ part){
  int blk = blockIdx.x;  // 512 = b(4) x ch(128), 16 rows each
  int b = blk>>7, ch = blk&127, t = threadIdx.x;
  const float* src = (t<128)? gemb : vemb;
  int d = t&127;
  float s=0.f;
  int n0 = ch*16;
  for(int n=0;n<16;++n) s += src[((size_t)(b*2048+n0+n))*128 + d];
  part[(size_t)blk*256 + t] = s;
}
__global__ void k_router(const float* __restrict__ part, const float* __restrict__ w1,
     const float* __restrict__ b1, const float* __restrict__ lg, const float* __restrict__ lb,
     const float* __restrict__ w2, const float* __restrict__ b2,
     float* __restrict__ rw, float* __restrict__ outrw){
  __shared__ float ri[256]; __shared__ float red[2];
  int b = blockIdx.x, t = threadIdx.x;  // 128 threads
  for(int j=t; j<256; j+=128){
    float s=0.f;
    for(int c=0;c<128;++c) s += part[(size_t)(b*128+c)*256 + j];
    ri[j] = s*(1.f/2048.f);
  }
  __syncthreads();
  float a = b1[t];
  for(int j=0;j<256;++j) a += ri[j]*w1[t*256+j];
  float mu = bsum<2>(a,red)*(1.f/128.f);
  float df = a-mu;
  float var = bsum<2>(df*df,red)*(1.f/128.f);
  float hv = fmaxf(df*rsqrtf(var+1e-5f)*lg[t]+lb[t], 0.f);
  float l0 = bsum<2>(hv*w2[t],red);
  float l1 = bsum<2>(hv*w2[128+t],red);
  float l2 = bsum<2>(hv*w2[256+t],red);
  if(t==0){
    l0+=b2[0]; l1+=b2[1]; l2+=b2[2];
    float mx = fmaxf(l0,fmaxf(l1,l2));
    float e0=__expf(l0-mx), e1=__expf(l1-mx), e2=__expf(l2-mx);
    float s=e0+e1+e2;
    rw[b*3+0]=e0/s; rw[b*3+1]=e1/s; rw[b*3+2]=e2/s;
    outrw[b*3+0]=e0/s; outrw[b*3+1]=e1/s; outrw[b*3+2]=e2/s;
  }
}

// ---------------- fused NetVLAD assign+aggregate (MFMA), per 64-row chunk ----------------
__global__ __launch_bounds__(256) void k_vlad1(
      const float* __restrict__ GE, const float* __restrict__ VE, const float* __restrict__ FU,
      const unsigned short* __restrict__ WBcw, const float* __restrict__ cbp,
      float* __restrict__ p0, float* __restrict__ p1, float* __restrict__ p2,
      float* __restrict__ asump){
  int ch = blockIdx.x, b = blockIdx.y, z = blockIdx.z;
  const float* feat = (z==0)?GE:((z==1)?VE:FU);
  const unsigned short* cwb = WBcw + z*8192;
  const float* cb = cbp + z*64;
  float* part = (z==0)?p0:((z==1)?p1:p2);
  float* asu = asump + z*8192;
  int t = threadIdx.x;
  __shared__ unsigned xnbu[64*36];
  __shared__ unsigned short xnbT[128*72];
  __shared__ unsigned abTu[64*36];
  int nbase = b*2048 + ch*64;
  {
    int r = t>>2, q = t&3;
    const float* frow = feat + (size_t)(nbase + r)*128 + q*32;
    float v[32]; float ssq = 0.f;
    #pragma unroll
    for(int i=0;i<8;++i){
      float4 f4 = *(const float4*)(frow + i*4);
      v[i*4+0]=f4.x; v[i*4+1]=f4.y; v[i*4+2]=f4.z; v[i*4+3]=f4.w;
      ssq += f4.x*f4.x+f4.y*f4.y+f4.z*f4.z+f4.w*f4.w;
    }
    ssq += __shfl_xor(ssq,1); ssq += __shfl_xor(ssq,2);
    float inv = 1.f/fmaxf(sqrtf(ssq),1e-12f);
    #pragma unroll
    for(int i=0;i<16;++i)
      xnbu[r*36 + q*8 + i] = pkbf(v[2*i]*inv, v[2*i+1]*inv);
    #pragma unroll
    for(int j=0;j<32;++j)
      xnbT[(q*32+j)*72 + r] = bf16c(v[j]*inv);
  }
  __syncthreads();
  int w = t>>6, lane = t&63, lr = lane&15, lg = lane>>4;
  {
    f32x4 acc[4] = {};
    #pragma unroll
    for(int ks=0; ks<4; ++ks){
      FR af; af.q = *(const uint4*)&xnbu[(w*16+lr)*36 + ks*16 + lg*4];
      #pragma unroll
      for(int nt=0; nt<4; ++nt){
        FR bf; bf.v = *(const s16x8*)(cwb + (size_t)(nt*16+lr)*128 + ks*32 + lg*8);
        acc[nt] = MF(af.v, bf.v, acc[nt]);
      }
    }
    float p[4][4]; float srow[4] = {0.f,0.f,0.f,0.f};
    #pragma unroll
    for(int nt=0;nt<4;++nt){
      float cbv = cb[nt*16+lr];
      #pragma unroll
      for(int rr=0;rr<4;++rr){
        p[nt][rr] = __expf(acc[nt][rr] + cbv);
        srow[rr] += p[nt][rr];
      }
    }
    #pragma unroll
    for(int rr=0;rr<4;++rr){
      float s = srow[rr];
      s += __shfl_xor(s,1); s += __shfl_xor(s,2); s += __shfl_xor(s,4); s += __shfl_xor(s,8);
      srow[rr] = 1.f/s;
    }
    #pragma unroll
    for(int nt=0;nt<4;++nt){
      int k = nt*16+lr;
      abTu[k*36 + w*8 + lg*2 + 0] = pkbf(p[nt][0]*srow[0], p[nt][1]*srow[1]);
      abTu[k*36 + w*8 + lg*2 + 1] = pkbf(p[nt][2]*srow[2], p[nt][3]*srow[3]);
    }
  }
  __syncthreads();
  {
    f32x4 acc[8] = {};
    #pragma unroll
    for(int ns=0; ns<2; ++ns){
      FR af; af.q = *(const uint4*)&abTu[(w*16+lr)*36 + ns*16 + lg*4];
      #pragma unroll
      for(int nt=0; nt<8; ++nt){
        FR bf; bf.v = *(const s16x8*)&xnbT[(nt*16+lr)*72 + ns*32 + lg*8];
        acc[nt] = MF(af.v, bf.v, acc[nt]);
      }
    }
    size_t pb = ((size_t)(b*32+ch)*64);
    #pragma unroll
    for(int nt=0; nt<8; ++nt){
      #pragma unroll
      for(int rr=0; rr<4; ++rr){
        int k = w*16+lg*4+rr;
        part[(pb + k)*128 + nt*16+lr] = acc[nt][rr];
      }
    }
  }
  if(t<64){
    float s = 0.f;
    #pragma unroll
    for(int i=0;i<32;++i){
      unsigned u = abTu[t*36+i];
      s += ubf_lo(u) + ubf_hi(u);
    }
    asu[((size_t)(b*32+ch))*64 + t] = s;
  }
}

// ---- vlad stage 2 (z-batched): reduce partials, subtract centers, l2n ----
__global__ void k_vagg2(
      const float* __restrict__ p0, const float* __restrict__ p1, const float* __restrict__ p2,
      const float* __restrict__ asump, const float* __restrict__ cent, float* __restrict__ vlad3){
  int k = blockIdx.x, b = blockIdx.y, z = blockIdx.z;   // grid (64,4,3), 128 thr
  const float* part = (z==0)?p0:((z==1)?p1:p2);
  const float* asu = asump + z*8192;
  const float* centp = cent + (size_t)z*8192;
  float* vlad = vlad3 + z*32768;
  int t = threadIdx.x;
  __shared__ float red[2];
  float v = 0.f;
  const float* pp = part + (((size_t)b*32)*64 + k)*128 + t;
  for(int ch=0; ch<32; ++ch) v += pp[(size_t)ch*8192];
  float as = 0.f;
  const float* ap = asu + (size_t)b*2048 + k;
  for(int ch=0; ch<32; ++ch) as += ap[(size_t)ch*64];
  v -= as * centp[(size_t)k*128 + t];
  float ssq = bsum<2>(v*v, red);
  float inv = 1.f/fmaxf(sqrtf(ssq),1e-12f);
  vlad[((size_t)b*64+k)*128+t] = v*inv;
}

// ---- descriptor GEMV v2: split-K, weights read exactly once ----
// grid (64 jg, 8 ks, 3 z), 256 thr (4 j per block, one wave per j)
__global__ __launch_bounds__(256) void k_desc(const float* __restrict__ vlad3,
      const float* __restrict__ bnw, float* __restrict__ PARTD){
  int jg = blockIdx.x, ks = blockIdx.y, z = blockIdx.z;
  int t = threadIdx.x, j2 = t>>6, lane = t&63;
  const float* vb = vlad3 + z*32768 + ks*1024;
  float vreg[4][16];
  #pragma unroll
  for(int b=0;b<4;++b)
    #pragma unroll
    for(int i=0;i<16;++i) vreg[b][i] = vb[b*8192 + i*64 + lane];
  int j = jg*4 + j2;
  const float* wrow = bnw + (size_t)z*2097152 + (size_t)j*8192 + ks*1024;
  float acc0=0.f, acc1=0.f, acc2=0.f, acc3=0.f;
  #pragma unroll
  for(int i=0;i<16;++i){
    float w = wrow[i*64+lane];
    acc0 += w*vreg[0][i];
    acc1 += w*vreg[1][i];
    acc2 += w*vreg[2][i];
    acc3 += w*vreg[3][i];
  }
  #pragma unroll
  for(int m=1;m<64;m<<=1){
    acc0 += __shfl_xor(acc0,m); acc1 += __shfl_xor(acc1,m);
    acc2 += __shfl_xor(acc2,m); acc3 += __shfl_xor(acc3,m);
  }
  if(lane==0){
    float* pd = PARTD + (((size_t)z*256 + j)*4)*8 + ks;
    pd[0]  = acc0;
    pd[8]  = acc1;
    pd[16] = acc2;
    pd[24] = acc3;
  }
}

// ---------------- final: flat-norm + split-K reduce + LN + l2n + mix ----------------
__global__ void k_final(const float* __restrict__ PARTD, const float* __restrict__ vlad3,
      const float* __restrict__ bnb, const float* __restrict__ lg,
      const float* __restrict__ lb, const float* __restrict__ rw, float* __restrict__ outp){
  __shared__ float red[4];
  int b = blockIdx.x, t = threadIdx.x;  // 256
  float inv3[3];
  #pragma unroll
  for(int z=0;z<3;++z){
    const float* vp = vlad3 + z*32768 + b*8192;
    float ss = 0.f;
    for(int i=t;i<8192;i+=256){ float v = vp[i]; ss += v*v; }
    ss = bsum<4>(ss, red);
    inv3[z] = 1.f/fmaxf(sqrtf(ss),1e-12f);
  }
  float acc = 0.f;
  for(int i=0;i<3;++i){
    const float* pd = PARTD + (((size_t)i*256 + t)*4 + b)*8;
    float s = 0.f;
    #pragma unroll
    for(int ks=0;ks<8;++ks) s += pd[ks];
    float x = s*inv3[i] + bnb[i*256+t];
    float mu = bsum<4>(x,red)*(1.f/256.f);
    float df = x-mu;
    float var = bsum<4>(df*df,red)*(1.f/256.f);
    float y = df*rsqrtf(var+1e-5f)*lg[i*256+t]+lb[i*256+t];
    float n2 = bsum<4>(y*y,red);
    y = y / fmaxf(sqrtf(n2),1e-12f);
    acc += rw[b*3+i]*y;
  }
  float n2 = bsum<4>(acc*acc,red);
  outp[(size_t)b*256+t] = acc/fmaxf(sqrtf(n2),1e-12f);
}

// ---------------- host ----------------
extern "C" void kernel_launch(void* const* d_in, const int* in_sizes, int n_in,
                              void* d_out, int out_size, void* d_ws, size_t ws_size,
                              hipStream_t stream){
  const float* gaussians=(const float*)d_in[0];
  const float* visual=(const float*)d_in[1];
  const float* extr=(const float*)d_in[2];
  const float* intr=(const float*)d_in[3];
  const float* offs=(const float*)d_in[4];
  const float* pg_w=(const float*)d_in[5];
  const float* pg_b=(const float*)d_in[6];
  const float* pg_g=(const float*)d_in[7];
  const float* pg_bb=(const float*)d_in[8];
  const float* pv_w=(const float*)d_in[9];
  const float* pv_b=(const float*)d_in[10];
  const float* pv_g=(const float*)d_in[11];
  const float* pv_bb=(const float*)d_in[12];
  const float* ipw=(const float*)d_in[13];
  const float* ipb=(const float*)d_in[14];
  const float* ow=(const float*)d_in[15];
  const float* ob=(const float*)d_in[16];
  const float* dg=(const float*)d_in[17];
  const float* db=(const float*)d_in[18];
  const float* gate_w=(const float*)d_in[19];
  const float* gate_b=(const float*)d_in[20];
  const float* rw1=(const float*)d_in[21];
  const float* rb1=(const float*)d_in[22];
  const float* rlg=(const float*)d_in[23];
  const float* rlb=(const float*)d_in[24];
  const float* rw2=(const float*)d_in[25];
  const float* rb2=(const float*)d_in[26];
  const float* cent=(const float*)d_in[27];
  const float* cw=(const float*)d_in[28];
  const float* cb=(const float*)d_in[29];
  const float* bnw=(const float*)d_in[30];
  const float* bnb=(const float*)d_in[31];
  const float* blg=(const float*)d_in[32];
  const float* blb=(const float*)d_in[33];
  float* outp=(float*)d_out;
  float* ws=(float*)d_ws;

  // ws map (floats), high-water ~11.40M floats (~45.6MB); 48.2MB proven usable (r2)
  float* VF  = ws + 1048576;         // 0.5M
  float* GE  = ws + 1572864;         // 1M (live through vlad1)
  float* VE  = ws + 2621440;         // 1M (live through vlad1)
  unsigned short* GEb = (unsigned short*)(ws + 3670016);   // dead post-qkv -> PART0
  unsigned short* VEb = (unsigned short*)(ws + 4194304);
  unsigned* QKVu = (unsigned*)(ws + 4718592);              // 3M; dead post-flash
  float* CC  = ws + 4718592;         // 2M (post-flash)
  unsigned short* CCb = (unsigned short*)(ws + 6815744);   // 1M floats worth (post-flash)
  unsigned* OPARTw = (unsigned*)(ws + 7864320);            // 2M words; dead post-oproj
  float* FU  = ws + 8912896;         // 1M (written by gatef, after OPART dead)
  unsigned short* WB = (unsigned short*)(ws + 9961472);    // 94208 floats worth
  float* PARTD = ws + 10072064;      // 24576
  float* RW  = ws + 10096640;        // 16
  float* VLAD3 = ws + 10096656;      // 98304
  float* PART2 = ws + 10194960;      // 1M
  float* ASUMP3 = ws + 11243536;     // 24576
  float* LSUM  = ws + 11268112;      // 131072 (flash phase)
  float* RP    = ws + 11268112;      // 131072 (pre-flash; router consumes before flash writes LSUM)
  float* PART0 = ws + 3670016;       // over GEb/VEb (dead post-qkv)
  float* PART1 = ws + 7864320;       // over OPART (dead post-oproj)
  const unsigned short* QKVh = (const unsigned short*)QKVu;

  k_proj<<<2048,256,0,stream>>>(gaussians, visual, extr, intr, offs, VF);
  k_embed<<<8192,128,0,stream>>>(gaussians, VF, pg_w,pg_b,pg_g,pg_bb,
                                 pv_w,pv_b,pv_g,pv_bb, GE, VE, GEb, VEb);
  k_rpart<<<512,256,0,stream>>>(GE, VE, RP);
  k_router<<<4,128,0,stream>>>(RP, rw1,rb1,rlg,rlb,rw2,rb2, RW, outp+1024);
  k_wprep<<<736,256,0,stream>>>(ipw, ow, gate_w, cw, WB);

  const float qsc = 1.4426950408889634f * 0.17677669529663687f;  // log2e/sqrt(32)
  k_qkv<<<dim3(128,12),256,0,stream>>>(GEb, VEb, WB, ipb, QKVu, qsc);
  k_flash<<<dim3(32,4,16),256,0,stream>>>(QKVh, OPARTw, LSUM);
  k_oproj<<<dim3(128,2),256,0,stream>>>(OPARTw, LSUM, WB, ob, GE, VE, dg, db, CC, CCb);
  k_gatef<<<dim3(128,2),256,0,stream>>>(CCb, WB, gate_b, CC, FU);
  k_vlad1<<<dim3(32,4,3),256,0,stream>>>(GE, VE, FU, WB+163840, cb,
                                         PART0, PART1, PART2, ASUMP3);
  k_vagg2<<<dim3(64,4,3),128,0,stream>>>(PART0,PART1,PART2, ASUMP3, cent, VLAD3);
  k_desc<<<dim3(64,8,3),256,0,stream>>>(VLAD3, bnw, PARTD);
  k_final<<<4,256,0,stream>>>(PARTD, VLAD3, bnb, blg, blb, RW, outp);
}

// Round 17
// 204.229 us; speedup vs baseline: 1.0464x; 1.0464x over previous
//
#include <hip/hip_runtime.h>
#include <math.h>

// ---------------- types & helpers ----------------
typedef float f32x4 __attribute__((ext_vector_type(4)));
typedef short s16x8 __attribute__((ext_vector_type(8)));

#define DEV static __device__ __forceinline__

DEV float wsum(float v){
  #pragma unroll
  for(int m=1;m<64;m<<=1) v += __shfl_xor(v,m);
  return v;
}
template<int NW>
DEV float bsum(float v, float* s){
  v = wsum(v);
  int w = threadIdx.x>>6;
  if((threadIdx.x&63)==0) s[w]=v;
  __syncthreads();
  float r = 0.f;
  #pragma unroll
  for(int i=0;i<NW;++i) r += s[i];
  __syncthreads();
  return r;
}
DEV float xexp2(float x){
#if __has_builtin(__builtin_amdgcn_exp2f)
  return __builtin_amdgcn_exp2f(x);
#else
  return exp2f(x);
#endif
}
DEV unsigned pkbf(float lo, float hi){
  unsigned r;
  asm("v_cvt_pk_bf16_f32 %0, %1, %2" : "=v"(r) : "v"(lo), "v"(hi));
  return r;
}
DEV unsigned short bf16c(float v){ return (unsigned short)(pkbf(v, 0.f) & 0xffffu); }
DEV float ubf_lo(unsigned u){ unsigned b=(u&0xffffu)<<16; return __builtin_bit_cast(float,b); }
DEV float ubf_hi(unsigned u){ unsigned b=(u>>16)<<16;    return __builtin_bit_cast(float,b); }
union FR { unsigned u[4]; s16x8 v; uint4 q; };

DEV f32x4 MF(s16x8 a, s16x8 b, f32x4 c){
  return __builtin_amdgcn_mfma_f32_16x16x32_bf16(a, b, c, 0,0,0);
}

// async global -> LDS, 16B per lane; dest = wave-uniform base + lane*16
DEV void gl_lds16(const void* g, void* l){
  __builtin_amdgcn_global_load_lds(
    (const __attribute__((address_space(1))) void*)g,
    (__attribute__((address_space(3))) void*)l, 16, 0, 0);
}

// ---------------- projection + bilinear sample -> vfeat [B,N,64] ----------------
__global__ __launch_bounds__(256) void k_proj(const float* __restrict__ gs, const float* __restrict__ vf,
                       const float* __restrict__ E, const float* __restrict__ Kin,
                       const float* __restrict__ off, float* __restrict__ vfeat){
  int bn = blockIdx.x*4 + (threadIdx.x>>6); int b = bn>>11; int c = threadIdx.x&63;
  const float* g = gs + (size_t)bn*14;
  float px = g[0], py = g[1], pz = g[2];
  float ox = off[bn*2+0], oy = off[bn*2+1];
  float acc = 0.f, vsum = 0.f;
  for(int v=0; v<4; ++v){
    const float* e = E + ((b*4+v)*16);
    float cx = e[0]*px + e[1]*py + e[2]*pz + e[3];
    float cy = e[4]*px + e[5]*py + e[6]*pz + e[7];
    float cz = e[8]*px + e[9]*py + e[10]*pz + e[11];
    const float* kk = Kin + ((b*4+v)*9);
    float ux = kk[0]*cx + kk[1]*cy + kk[2]*cz;
    float uy = kk[3]*cx + kk[4]*cy + kk[5]*cz;
    float uz = kk[6]*cx + kk[7]*cy + kk[8]*cz;
    float dep = fmaxf(uz, 1e-6f);
    float gx = 2.f*(ux/dep)*(1.f/448.f) - 1.f + ox;
    float gy = 2.f*(uy/dep)*(1.f/448.f) - 1.f + oy;
    float valid = (uz > 0.1f && gx >= -1.f && gx <= 1.f && gy >= -1.f && gy <= 1.f) ? 1.f : 0.f;
    float x = (gx+1.f)*16.f - 0.5f;
    float y = (gy+1.f)*16.f - 0.5f;
    float x0 = floorf(x), y0 = floorf(y);
    const float* fbase = vf + (size_t)((b*4+v)*64 + c)*1024;
    float sv = 0.f;
    #pragma unroll
    for(int t=0;t<4;++t){
      float xi = x0 + (float)(t&1), yi = y0 + (float)(t>>1);
      float wgt = (1.f - fabsf(x-xi))*(1.f - fabsf(y-yi));
      bool vt = (xi>=0.f && xi<32.f && yi>=0.f && yi<32.f);
      int xc = (int)fminf(fmaxf(xi,0.f),31.f);
      int yc = (int)fminf(fmaxf(yi,0.f),31.f);
      float smp = fbase[yc*32+xc];
      sv += vt ? wgt*smp : 0.f;
    }
    acc += valid * sv;
    vsum += valid;
  }
  vfeat[(size_t)bn*64 + c] = acc / (vsum + 1e-8f);
}

// ---------------- embed: g_emb / v_emb = relu(LN(x@W^T+b)) + bf16 copies ----------------
__global__ void k_embed(const float* __restrict__ gs, const float* __restrict__ vfeat,
   const float* __restrict__ pg_w, const float* __restrict__ pg_b,
   const float* __restrict__ pg_g, const float* __restrict__ pg_bb,
   const float* __restrict__ pv_w, const float* __restrict__ pv_b,
   const float* __restrict__ pv_g, const float* __restrict__ pv_bb,
   float* __restrict__ gemb, float* __restrict__ vemb,
   unsigned short* __restrict__ gembb, unsigned short* __restrict__ vembb){
  __shared__ float xs[64]; __shared__ float gsr[14]; __shared__ float red[2];
  int row = blockIdx.x; int d = threadIdx.x;
  if(d<14) gsr[d] = gs[(size_t)row*14+d];
  if(d<64) xs[d] = vfeat[(size_t)row*64+d];
  __syncthreads();
  float a = pg_b[d];
  #pragma unroll
  for(int j=0;j<14;++j) a += gsr[j]*pg_w[d*14+j];
  float mu = bsum<2>(a, red)*(1.f/128.f);
  float df = a-mu;
  float var = bsum<2>(df*df, red)*(1.f/128.f);
  float y = fmaxf(df*rsqrtf(var+1e-5f)*pg_g[d] + pg_bb[d], 0.f);
  gemb[(size_t)row*128+d] = y;
  gembb[(size_t)row*128+d] = bf16c(y);
  float av = pv_b[d];
  #pragma unroll
  for(int j=0;j<64;++j) av += xs[j]*pv_w[d*64+j];
  mu = bsum<2>(av, red)*(1.f/128.f);
  df = av-mu;
  var = bsum<2>(df*df, red)*(1.f/128.f);
  y = fmaxf(df*rsqrtf(var+1e-5f)*pv_g[d] + pv_bb[d], 0.f);
  vemb[(size_t)row*128+d] = y;
  vembb[(size_t)row*128+d] = bf16c(y);
}

// ---------------- weights -> bf16 (ipw | ow | gate_w | cw) ----------------
__global__ void k_wprep(const float* __restrict__ ipw, const float* __restrict__ ow,
                        const float* __restrict__ gw, const float* __restrict__ cw,
                        unsigned short* __restrict__ WB){
  int i = blockIdx.x*256 + threadIdx.x;   // 188416
  if(i >= 188416) return;
  float v;
  if(i < 98304)       v = ipw[i];
  else if(i < 131072) v = ow[i-98304];
  else if(i < 163840) v = gw[i-131072];
  else                v = cw[i-163840];
  WB[i] = bf16c(v);
}

// ---------------- fused QKV projection -> flash layout (bf16) ----------------
__global__ __launch_bounds__(256) void k_qkv(const unsigned short* __restrict__ GEb,
    const unsigned short* __restrict__ VEb, const unsigned short* __restrict__ WB,
    const float* __restrict__ ipb, unsigned* __restrict__ QKVu, float qsc){
  int mt = blockIdx.x, y = blockIdx.y;
  int m = y/6, j6 = y%6, kind = j6>>1, n0 = (j6&1)*64;
  const unsigned short* A = (kind==0) ? (m?VEb:GEb) : (m?GEb:VEb);
  const unsigned short* W = WB + m*49152 + kind*16384;
  const float* bias = ipb + m*384 + kind*128;
  unsigned* outb = QKVu + (size_t)m*1572864 + (size_t)kind*524288;
  float scale = (kind==0)? qsc : 1.f;
  int m0 = mt*64;
  int wid=threadIdx.x>>6, lane=threadIdx.x&63, lr=lane&15, lg=lane>>4;
  const unsigned short* ap = A + (size_t)(m0+wid*16+lr)*128 + lg*8;
  f32x4 acc[4] = {{0,0,0,0},{0,0,0,0},{0,0,0,0},{0,0,0,0}};
  #pragma unroll
  for(int ks=0; ks<128; ks+=32){
    FR af; af.v = *(const s16x8*)(ap + ks);
    #pragma unroll
    for(int nt=0; nt<4; ++nt){
      FR bf; bf.v = *(const s16x8*)(W + (size_t)(n0+nt*16+lr)*128 + ks + lg*8);
      acc[nt] = MF(af.v, bf.v, acc[nt]);
    }
  }
  __shared__ float xs[64][65];
  #pragma unroll
  for(int nt=0; nt<4; ++nt){
    float bv = bias[n0+nt*16+lr];
    #pragma unroll
    for(int r=0;r<4;++r) xs[wid*16+lg*4+r][nt*16+lr] = (acc[nt][r]+bv)*scale;
  }
  __syncthreads();
  if(kind<2){
    int i = threadIdx.x>>2, s = threadIdx.x&3;
    int gr = m0 + i, b = gr>>11, nn = gr&2047;
    int j0 = n0 + s*16, h = j0>>5, d0 = j0&31;
    unsigned w[8];
    #pragma unroll
    for(int p=0;p<8;++p) w[p] = pkbf(xs[i][s*16+2*p], xs[i][s*16+2*p+1]);
    unsigned* dst = outb + ((size_t)(b*4+h)*2048+nn)*16 + (d0>>1);
    uint4 u0; u0.x=w[0];u0.y=w[1];u0.z=w[2];u0.w=w[3];
    uint4 u1; u1.x=w[4];u1.y=w[5];u1.z=w[6];u1.w=w[7];
    *(uint4*)dst = u0; *(uint4*)(dst+4) = u1;
  } else {
    int c = threadIdx.x>>2, rs = threadIdx.x&3;
    int j = n0 + c, h = j>>5, d = j&31;
    int b = m0>>11, nn0 = m0&2047;
    unsigned w[8];
    #pragma unroll
    for(int p=0;p<8;++p) w[p] = pkbf(xs[rs*16+2*p][c], xs[rs*16+2*p+1][c]);
    unsigned* dst = outb + (size_t)(b*4+h)*32768 + (size_t)d*1024 + ((nn0+rs*16)>>1);
    uint4 u0; u0.x=w[0];u0.y=w[1];u0.z=w[2];u0.w=w[3];
    uint4 u1; u1.x=w[4];u1.y=w[5];u1.z=w[6];u1.w=w[7];
    *(uint4*)dst = u0; *(uint4*)(dst+4) = u1;
  }
}

// ---------------- MFMA bf16 flash attention v9 (r13/r15 best): LDS staging, K+V XOR-swizzled ----------------
__global__ __launch_bounds__(256) void k_flash(const unsigned short* __restrict__ QKV,
    unsigned* __restrict__ OPARTw, float* __restrict__ LSUM){
  int qt = blockIdx.x, h = blockIdx.y, z = blockIdx.z;   // grid (32,4,16)
  int mb = z&7, split = z>>3;
  int m = mb>>2, b = mb&3;
  const unsigned short* base = QKV + (size_t)m*3145728;
  const unsigned short* qp = base + (size_t)(b*4+h)*65536;
  const unsigned short* kp = qp + 1048576;
  const unsigned short* vp = qp + 2097152;
  int tid=threadIdx.x, wid=tid>>6, lane=tid&63, lr=lane&15, lg=lane>>4;
  __shared__ unsigned short KT[2][2048];
  __shared__ unsigned short VT[2][2048];
  __shared__ unsigned Ps[4][16][33];
  int q0 = qt*64 + wid*16;
  int kbase = split*1024;
  FR qf; qf.v = *(const s16x8*)(qp + (size_t)(q0+lr)*32 + lg*8);
  const f32x4 zz = {0.f,0.f,0.f,0.f};
  f32x4 o0g = zz, o1g = zz;
  float lrun = 0.f;
  unsigned* prow = &Ps[wid][lr][0];
  int kr = wid*16 + (lane>>2);
  int kscol = (((lane&3)<<3) ^ (((lane>>3)&3)<<3));
  const unsigned short* ksrc0 = kp + (size_t)(kbase + kr)*32 + kscol;
  int vrow = wid*8 + (lane>>3);
  int vscol = 8*((lane&7) ^ (lane>>3));
  const unsigned short* vsrc0 = vp + (size_t)vrow*2048 + kbase + vscol;
  int kkey = ((lr>>1)&3)<<3;
  int ko = lr*32 + ((lg*8) ^ kkey);
  int sw = (lr&7)*8;
  int vo0 = lr*64 + ((lg*8) ^ sw);
  int vo2 = lr*64 + ((32+lg*8) ^ sw);
  gl_lds16(ksrc0, &KT[0][wid*512]);
  gl_lds16(vsrc0, &VT[0][wid*512]);
  __syncthreads();
  int buf = 0;
  for(int t=0; t<16; ++t){
    int tn = (t+1)&15;
    gl_lds16(ksrc0 + (size_t)tn*2048, &KT[buf^1][wid*512]);
    gl_lds16(vsrc0 + tn*64,           &VT[buf^1][wid*512]);
    const unsigned short* Ktb = &KT[buf][0];
    const unsigned short* Vtb = &VT[buf][0];
    FR k0,k1,k2,k3;
    k0.v = *(const s16x8*)(Ktb + ko);
    k1.v = *(const s16x8*)(Ktb +  512 + ko);
    k2.v = *(const s16x8*)(Ktb + 1024 + ko);
    k3.v = *(const s16x8*)(Ktb + 1536 + ko);
    f32x4 s0 = MF(k0.v, qf.v, zz);
    f32x4 s1 = MF(k1.v, qf.v, zz);
    f32x4 s2 = MF(k2.v, qf.v, zz);
    f32x4 s3 = MF(k3.v, qf.v, zz);
    float p0[4],p1[4],p2[4],p3[4]; float ps=0.f;
    #pragma unroll
    for(int r=0;r<4;++r){
      p0[r]=xexp2(s0[r]); p1[r]=xexp2(s1[r]);
      p2[r]=xexp2(s2[r]); p3[r]=xexp2(s3[r]);
      ps += p0[r]+p1[r]+p2[r]+p3[r];
    }
    lrun += ps;
    asm volatile("" ::: "memory");
    prow[   lg*2+0]=pkbf(p0[0],p0[1]); prow[   lg*2+1]=pkbf(p0[2],p0[3]);
    prow[ 8+lg*2+0]=pkbf(p1[0],p1[1]); prow[ 8+lg*2+1]=pkbf(p1[2],p1[3]);
    prow[16+lg*2+0]=pkbf(p2[0],p2[1]); prow[16+lg*2+1]=pkbf(p2[2],p2[3]);
    prow[24+lg*2+0]=pkbf(p3[0],p3[1]); prow[24+lg*2+1]=pkbf(p3[2],p3[3]);
    asm volatile("" ::: "memory");
    FR pf0, pf1;
    #pragma unroll
    for(int i=0;i<4;++i){ pf0.u[i]=prow[lg*4+i]; pf1.u[i]=prow[16+lg*4+i]; }
    FR v0,v1,v2,v3;
    v0.v = *(const s16x8*)(Vtb + vo0);
    v1.v = *(const s16x8*)(Vtb + 1024 + vo0);
    v2.v = *(const s16x8*)(Vtb + vo2);
    v3.v = *(const s16x8*)(Vtb + 1024 + vo2);
    o0g = MF(v0.v, pf0.v, o0g);
    o1g = MF(v1.v, pf0.v, o1g);
    o0g = MF(v2.v, pf1.v, o0g);
    o1g = MF(v3.v, pf1.v, o1g);
    __syncthreads();
    buf ^= 1;
  }
  lrun += __shfl_xor(lrun,16); lrun += __shfl_xor(lrun,32);
  unsigned w00=pkbf(o0g[0],o0g[1]), w01=pkbf(o0g[2],o0g[3]);
  unsigned w10=pkbf(o1g[0],o1g[1]), w11=pkbf(o1g[2],o1g[3]);
  unsigned* op = OPARTw + ((size_t)(split*2+m)*8192 + (size_t)(b*2048+q0+lr))*64 + h*16 + lg*2;
  op[0]=w00; op[1]=w01; op[8]=w10; op[9]=w11;
  if(lg==0) LSUM[((size_t)(split*2+m)*16 + b*4+h)*2048 + q0+lr] = lrun;
}

// ---------------- fused split-K merge + out-proj GEMM + bias + residual + LN ----------------
__global__ __launch_bounds__(256) void k_oproj(const unsigned* __restrict__ OPARTw,
    const float* __restrict__ LSUM,
    const unsigned short* __restrict__ WB, const float* __restrict__ ob,
    const float* __restrict__ GE, const float* __restrict__ VE,
    const float* __restrict__ dg, const float* __restrict__ db,
    float* __restrict__ CC, unsigned short* __restrict__ CCb){
  int mt = blockIdx.x, m = blockIdx.y;
  int m0 = mt*64;
  const unsigned short* W = WB + 98304 + m*16384;
  const float* bias = ob + m*128;
  const float* R = m ? VE : GE;
  const float* gamma = dg + m*128;
  const float* beta  = db + m*128;
  int wid=threadIdx.x>>6, lane=threadIdx.x&63, lr=lane&15, lg=lane>>4;
  int gr = m0 + wid*16 + lr;
  int b2 = gr>>11, nn = gr&2047;
  float invh[4];
  #pragma unroll
  for(int h=0;h<4;++h){
    float l0 = LSUM[((size_t)(m*16) + b2*4+h)*2048 + nn];
    float l1 = LSUM[((size_t)((2+m)*16) + b2*4+h)*2048 + nn];
    invh[h] = 1.f/(l0+l1);
  }
  const unsigned* a0 = OPARTw + ((size_t)m*8192 + gr)*64 + lg*4;
  const unsigned* a1 = OPARTw + ((size_t)(2+m)*8192 + gr)*64 + lg*4;
  f32x4 acc[8] = {};
  #pragma unroll
  for(int ks=0; ks<4; ++ks){
    uint4 u0 = *(const uint4*)(a0 + ks*16);
    uint4 u1 = *(const uint4*)(a1 + ks*16);
    float sc = invh[ks];
    FR af;
    af.u[0] = pkbf((ubf_lo(u0.x)+ubf_lo(u1.x))*sc, (ubf_hi(u0.x)+ubf_hi(u1.x))*sc);
    af.u[1] = pkbf((ubf_lo(u0.y)+ubf_lo(u1.y))*sc, (ubf_hi(u0.y)+ubf_hi(u1.y))*sc);
    af.u[2] = pkbf((ubf_lo(u0.z)+ubf_lo(u1.z))*sc, (ubf_hi(u0.z)+ubf_hi(u1.z))*sc);
    af.u[3] = pkbf((ubf_lo(u0.w)+ubf_lo(u1.w))*sc, (ubf_hi(u0.w)+ubf_hi(u1.w))*sc);
    #pragma unroll
    for(int nt=0; nt<8; ++nt){
      FR bf; bf.v = *(const s16x8*)(W + (size_t)(nt*16+lr)*128 + ks*32 + lg*8);
      acc[nt] = MF(af.v, bf.v, acc[nt]);
    }
  }
  __shared__ float xs[64][129];
  __shared__ float mus[64], rss[64];
  #pragma unroll
  for(int nt=0; nt<8; ++nt){
    float bv = bias[nt*16+lr];
    #pragma unroll
    for(int r=0;r<4;++r){
      int row = wid*16+lg*4+r;
      xs[row][nt*16+lr] = acc[nt][r] + bv + R[(size_t)(m0+row)*128 + nt*16+lr];
    }
  }
  __syncthreads();
  if(threadIdx.x < 64){
    int row = threadIdx.x;
    float s=0.f, s2=0.f;
    #pragma unroll 8
    for(int c=0;c<128;++c){ float x = xs[row][c]; s += x; s2 += x*x; }
    float mu = s*(1.f/128.f);
    float var = fmaxf(s2*(1.f/128.f) - mu*mu, 0.f);
    mus[row] = mu; rss[row] = rsqrtf(var + 1e-5f);
  }
  __syncthreads();
  int row = threadIdx.x>>2, cs = (threadIdx.x&3)*32;
  float mu = mus[row], rs = rss[row];
  size_t obase = (size_t)(m0+row)*256 + m*128;
  #pragma unroll 8
  for(int c=cs;c<cs+32;++c){
    float y = (xs[row][c]-mu)*rs*gamma[c] + beta[c];
    CC [obase + c] = y;
    CCb[obase + c] = bf16c(y);
  }
}

// ---------------- fused gate GEMM + sigmoid + mix -> FU (grid (128,2)) ----------------
__global__ __launch_bounds__(256) void k_gatef(const unsigned short* __restrict__ CCb,
    const unsigned short* __restrict__ WB, const float* __restrict__ gate_b,
    const float* __restrict__ CC, float* __restrict__ FU){
  int mt = blockIdx.x, nh = blockIdx.y;
  int m0 = mt*64, c0 = nh*64;
  const unsigned short* W = WB + 131072;
  int wid=threadIdx.x>>6, lane=threadIdx.x&63, lr=lane&15, lg=lane>>4;
  const unsigned short* ap = CCb + (size_t)(m0+wid*16+lr)*256 + lg*8;
  f32x4 acc[4] = {};
  #pragma unroll
  for(int ks=0; ks<256; ks+=32){
    FR af; af.v = *(const s16x8*)(ap + ks);
    #pragma unroll
    for(int nt=0; nt<4; ++nt){
      FR bf; bf.v = *(const s16x8*)(W + (size_t)(c0+nt*16+lr)*256 + ks + lg*8);
      acc[nt] = MF(af.v, bf.v, acc[nt]);
    }
  }
  #pragma unroll
  for(int nt=0; nt<4; ++nt){
    int col = c0 + nt*16+lr;
    float bv = gate_b[col];
    #pragma unroll
    for(int r=0;r<4;++r){
      int row = m0 + wid*16+lg*4+r;
      float gv = 1.f/(1.f+__expf(-(acc[nt][r]+bv)));
      FU[(size_t)row*128 + col] = CC[(size_t)row*256 + col]*gv
                                + CC[(size_t)row*256 + 128 + col]*(1.f-gv);
    }
  }
}

// ---------------- router ----------------
__global__ __launch_bounds__(256) void k_rpart(const float* __restrict__ gemb, const float* __restrict__ vemb,
                        float* __restrict__ part){
  int blk = blockIdx.x;  // 512 = b(4) x ch(128), 16 rows each
  int b = blk>>7, ch = blk&127, t = threadIdx.x;
  const float* src = (t<128)? gemb : vemb;
  int d = t&127;
  float s=0.f;
  int n0 = ch*16;
  for(int n=0;n<16;++n) s += src[((size_t)(b*2048+n0+n))*128 + d];
  part[(size_t)blk*256 + t] = s;
}
__global__ void k_router(const float* __restrict__ part, const float* __restrict__ w1,
     const float* __restrict__ b1, const float* __restrict__ lg, const float* __restrict__ lb,
     const float* __restrict__ w2, const float* __restrict__ b2,
     float* __restrict__ rw, float* __restrict__ outrw){
  __shared__ float ri[256]; __shared__ float red[2];
  int b = blockIdx.x, t = threadIdx.x;  // 128 threads
  for(int j=t; j<256; j+=128){
    float s=0.f;
    for(int c=0;c<128;++c) s += part[(size_t)(b*128+c)*256 + j];
    ri[j] = s*(1.f/2048.f);
  }
  __syncthreads();
  float a = b1[t];
  for(int j=0;j<256;++j) a += ri[j]*w1[t*256+j];
  float mu = bsum<2>(a,red)*(1.f/128.f);
  float df = a-mu;
  float var = bsum<2>(df*df,red)*(1.f/128.f);
  float hv = fmaxf(df*rsqrtf(var+1e-5f)*lg[t]+lb[t], 0.f);
  float l0 = bsum<2>(hv*w2[t],red);
  float l1 = bsum<2>(hv*w2[128+t],red);
  float l2 = bsum<2>(hv*w2[256+t],red);
  if(t==0){
    l0+=b2[0]; l1+=b2[1]; l2+=b2[2];
    float mx = fmaxf(l0,fmaxf(l1,l2));
    float e0=__expf(l0-mx), e1=__expf(l1-mx), e2=__expf(l2-mx);
    float s=e0+e1+e2;
    rw[b*3+0]=e0/s; rw[b*3+1]=e1/s; rw[b*3+2]=e2/s;
    outrw[b*3+0]=e0/s; outrw[b*3+1]=e1/s; outrw[b*3+2]=e2/s;
  }
}

// ---------------- fused NetVLAD assign+aggregate (MFMA), per 64-row chunk ----------------
__global__ __launch_bounds__(256) void k_vlad1(
      const float* __restrict__ GE, const float* __restrict__ VE, const float* __restrict__ FU,
      const unsigned short* __restrict__ WBcw, const float* __restrict__ cbp,
      float* __restrict__ p0, float* __restrict__ p1, float* __restrict__ p2,
      float* __restrict__ asump){
  int ch = blockIdx.x, b = blockIdx.y, z = blockIdx.z;
  const float* feat = (z==0)?GE:((z==1)?VE:FU);
  const unsigned short* cwb = WBcw + z*8192;
  const float* cb = cbp + z*64;
  float* part = (z==0)?p0:((z==1)?p1:p2);
  float* asu = asump + z*8192;
  int t = threadIdx.x;
  __shared__ unsigned xnbu[64*36];
  __shared__ unsigned short xnbT[128*72];
  __shared__ unsigned abTu[64*36];
  int nbase = b*2048 + ch*64;
  {
    int r = t>>2, q = t&3;
    const float* frow = feat + (size_t)(nbase + r)*128 + q*32;
    float v[32]; float ssq = 0.f;
    #pragma unroll
    for(int i=0;i<8;++i){
      float4 f4 = *(const float4*)(frow + i*4);
      v[i*4+0]=f4.x; v[i*4+1]=f4.y; v[i*4+2]=f4.z; v[i*4+3]=f4.w;
      ssq += f4.x*f4.x+f4.y*f4.y+f4.z*f4.z+f4.w*f4.w;
    }
    ssq += __shfl_xor(ssq,1); ssq += __shfl_xor(ssq,2);
    float inv = 1.f/fmaxf(sqrtf(ssq),1e-12f);
    #pragma unroll
    for(int i=0;i<16;++i)
      xnbu[r*36 + q*8 + i] = pkbf(v[2*i]*inv, v[2*i+1]*inv);
    #pragma unroll
    for(int j=0;j<32;++j)
      xnbT[(q*32+j)*72 + r] = bf16c(v[j]*inv);
  }
  __syncthreads();
  int w = t>>6, lane = t&63, lr = lane&15, lg = lane>>4;
  {
    f32x4 acc[4] = {};
    #pragma unroll
    for(int ks=0; ks<4; ++ks){
      FR af; af.q = *(const uint4*)&xnbu[(w*16+lr)*36 + ks*16 + lg*4];
      #pragma unroll
      for(int nt=0; nt<4; ++nt){
        FR bf; bf.v = *(const s16x8*)(cwb + (size_t)(nt*16+lr)*128 + ks*32 + lg*8);
        acc[nt] = MF(af.v, bf.v, acc[nt]);
      }
    }
    float p[4][4]; float srow[4] = {0.f,0.f,0.f,0.f};
    #pragma unroll
    for(int nt=0;nt<4;++nt){
      float cbv = cb[nt*16+lr];
      #pragma unroll
      for(int rr=0;rr<4;++rr){
        p[nt][rr] = __expf(acc[nt][rr] + cbv);
        srow[rr] += p[nt][rr];
      }
    }
    #pragma unroll
    for(int rr=0;rr<4;++rr){
      float s = srow[rr];
      s += __shfl_xor(s,1); s += __shfl_xor(s,2); s += __shfl_xor(s,4); s += __shfl_xor(s,8);
      srow[rr] = 1.f/s;
    }
    #pragma unroll
    for(int nt=0;nt<4;++nt){
      int k = nt*16+lr;
      abTu[k*36 + w*8 + lg*2 + 0] = pkbf(p[nt][0]*srow[0], p[nt][1]*srow[1]);
      abTu[k*36 + w*8 + lg*2 + 1] = pkbf(p[nt][2]*srow[2], p[nt][3]*srow[3]);
    }
  }
  __syncthreads();
  {
    f32x4 acc[8] = {};
    #pragma unroll
    for(int ns=0; ns<2; ++ns){
      FR af; af.q = *(const uint4*)&abTu[(w*16+lr)*36 + ns*16 + lg*4];
      #pragma unroll
      for(int nt=0; nt<8; ++nt){
        FR bf; bf.v = *(const s16x8*)&xnbT[(nt*16+lr)*72 + ns*32 + lg*8];
        acc[nt] = MF(af.v, bf.v, acc[nt]);
      }
    }
    size_t pb = ((size_t)(b*32+ch)*64);
    #pragma unroll
    for(int nt=0; nt<8; ++nt){
      #pragma unroll
      for(int rr=0; rr<4; ++rr){
        int k = w*16+lg*4+rr;
        part[(pb + k)*128 + nt*16+lr] = acc[nt][rr];
      }
    }
  }
  if(t<64){
    float s = 0.f;
    #pragma unroll
    for(int i=0;i<32;++i){
      unsigned u = abTu[t*36+i];
      s += ubf_lo(u) + ubf_hi(u);
    }
    asu[((size_t)(b*32+ch))*64 + t] = s;
  }
}

// ---- vlad stage 2 (z-batched): reduce partials, subtract centers, l2n ----
__global__ void k_vagg2(
      const float* __restrict__ p0, const float* __restrict__ p1, const float* __restrict__ p2,
      const float* __restrict__ asump, const float* __restrict__ cent, float* __restrict__ vlad3){
  int k = blockIdx.x, b = blockIdx.y, z = blockIdx.z;   // grid (64,4,3), 128 thr
  const float* part = (z==0)?p0:((z==1)?p1:p2);
  const float* asu = asump + z*8192;
  const float* centp = cent + (size_t)z*8192;
  float* vlad = vlad3 + z*32768;
  int t = threadIdx.x;
  __shared__ float red[2];
  float v = 0.f;
  const float* pp = part + (((size_t)b*32)*64 + k)*128 + t;
  for(int ch=0; ch<32; ++ch) v += pp[(size_t)ch*8192];
  float as = 0.f;
  const float* ap = asu + (size_t)b*2048 + k;
  for(int ch=0; ch<32; ++ch) as += ap[(size_t)ch*64];
  v -= as * centp[(size_t)k*128 + t];
  float ssq = bsum<2>(v*v, red);
  float inv = 1.f/fmaxf(sqrtf(ssq),1e-12f);
  vlad[((size_t)b*64+k)*128+t] = v*inv;
}

// ---- descriptor GEMV v3: split-K, weights once, float4 streams ----
// grid (64 jg, 8 ks, 3 z), 256 thr (4 j per block, one wave per j)
__global__ __launch_bounds__(256) void k_desc(const float* __restrict__ vlad3,
      const float* __restrict__ bnw, float* __restrict__ PARTD){
  int jg = blockIdx.x, ks = blockIdx.y, z = blockIdx.z;
  int t = threadIdx.x, j2 = t>>6, lane = t&63;
  const float4* vb = (const float4*)(vlad3 + z*32768 + ks*1024);
  float4 vr0_0 = vb[0*2048 + 0*64 + lane], vr0_1 = vb[0*2048 + 1*64 + lane],
         vr0_2 = vb[0*2048 + 2*64 + lane], vr0_3 = vb[0*2048 + 3*64 + lane];
  float4 vr1_0 = vb[1*2048 + 0*64 + lane], vr1_1 = vb[1*2048 + 1*64 + lane],
         vr1_2 = vb[1*2048 + 2*64 + lane], vr1_3 = vb[1*2048 + 3*64 + lane];
  float4 vr2_0 = vb[2*2048 + 0*64 + lane], vr2_1 = vb[2*2048 + 1*64 + lane],
         vr2_2 = vb[2*2048 + 2*64 + lane], vr2_3 = vb[2*2048 + 3*64 + lane];
  float4 vr3_0 = vb[3*2048 + 0*64 + lane], vr3_1 = vb[3*2048 + 1*64 + lane],
         vr3_2 = vb[3*2048 + 2*64 + lane], vr3_3 = vb[3*2048 + 3*64 + lane];
  int j = jg*4 + j2;
  const float4* wr = (const float4*)(bnw + (size_t)z*2097152 + (size_t)j*8192 + ks*1024);
  float acc0=0.f, acc1=0.f, acc2=0.f, acc3=0.f;
  {
    float4 w = wr[0*64+lane];
    acc0 += w.x*vr0_0.x + w.y*vr0_0.y + w.z*vr0_0.z + w.w*vr0_0.w;
    acc1 += w.x*vr1_0.x + w.y*vr1_0.y + w.z*vr1_0.z + w.w*vr1_0.w;
    acc2 += w.x*vr2_0.x + w.y*vr2_0.y + w.z*vr2_0.z + w.w*vr2_0.w;
    acc3 += w.x*vr3_0.x + w.y*vr3_0.y + w.z*vr3_0.z + w.w*vr3_0.w;
  }
  {
    float4 w = wr[1*64+lane];
    acc0 += w.x*vr0_1.x + w.y*vr0_1.y + w.z*vr0_1.z + w.w*vr0_1.w;
    acc1 += w.x*vr1_1.x + w.y*vr1_1.y + w.z*vr1_1.z + w.w*vr1_1.w;
    acc2 += w.x*vr2_1.x + w.y*vr2_1.y + w.z*vr2_1.z + w.w*vr2_1.w;
    acc3 += w.x*vr3_1.x + w.y*vr3_1.y + w.z*vr3_1.z + w.w*vr3_1.w;
  }
  {
    float4 w = wr[2*64+lane];
    acc0 += w.x*vr0_2.x + w.y*vr0_2.y + w.z*vr0_2.z + w.w*vr0_2.w;
    acc1 += w.x*vr1_2.x + w.y*vr1_2.y + w.z*vr1_2.z + w.w*vr1_2.w;
    acc2 += w.x*vr2_2.x + w.y*vr2_2.y + w.z*vr2_2.z + w.w*vr2_2.w;
    acc3 += w.x*vr3_2.x + w.y*vr3_2.y + w.z*vr3_2.z + w.w*vr3_2.w;
  }
  {
    float4 w = wr[3*64+lane];
    acc0 += w.x*vr0_3.x + w.y*vr0_3.y + w.z*vr0_3.z + w.w*vr0_3.w;
    acc1 += w.x*vr1_3.x + w.y*vr1_3.y + w.z*vr1_3.z + w.w*vr1_3.w;
    acc2 += w.x*vr2_3.x + w.y*vr2_3.y + w.z*vr2_3.z + w.w*vr2_3.w;
    acc3 += w.x*vr3_3.x + w.y*vr3_3.y + w.z*vr3_3.z + w.w*vr3_3.w;
  }
  #pragma unroll
  for(int m=1;m<64;m<<=1){
    acc0 += __shfl_xor(acc0,m); acc1 += __shfl_xor(acc1,m);
    acc2 += __shfl_xor(acc2,m); acc3 += __shfl_xor(acc3,m);
  }
  if(lane==0){
    float* pd = PARTD + (((size_t)z*256 + j)*4)*8 + ks;
    pd[0]  = acc0;
    pd[8]  = acc1;
    pd[16] = acc2;
    pd[24] = acc3;
  }
}

// ---------------- final: flat-norm + split-K reduce + LN + l2n + mix ----------------
__global__ void k_final(const float* __restrict__ PARTD, const float* __restrict__ vlad3,
      const float* __restrict__ bnb, const float* __restrict__ lg,
      const float* __restrict__ lb, const float* __restrict__ rw, float* __restrict__ outp){
  __shared__ float red[4];
  int b = blockIdx.x, t = threadIdx.x;  // 256
  float inv3[3];
  #pragma unroll
  for(int z=0;z<3;++z){
    const float4* vp = (const float4*)(vlad3 + z*32768 + b*8192);
    float ss = 0.f;
    for(int i=t;i<2048;i+=256){
      float4 v = vp[i];
      ss += v.x*v.x + v.y*v.y + v.z*v.z + v.w*v.w;
    }
    ss = bsum<4>(ss, red);
    inv3[z] = 1.f/fmaxf(sqrtf(ss),1e-12f);
  }
  float acc = 0.f;
  for(int i=0;i<3;++i){
    const float* pd = PARTD + (((size_t)i*256 + t)*4 + b)*8;
    float s = 0.f;
    #pragma unroll
    for(int ks=0;ks<8;++ks) s += pd[ks];
    float x = s*inv3[i] + bnb[i*256+t];
    float mu = bsum<4>(x,red)*(1.f/256.f);
    float df = x-mu;
    float var = bsum<4>(df*df,red)*(1.f/256.f);
    float y = df*rsqrtf(var+1e-5f)*lg[i*256+t]+lb[i*256+t];
    float n2 = bsum<4>(y*y,red);
    y = y / fmaxf(sqrtf(n2),1e-12f);
    acc += rw[b*3+i]*y;
  }
  float n2 = bsum<4>(acc*acc,red);
  outp[(size_t)b*256+t] = acc/fmaxf(sqrtf(n2),1e-12f);
}

// ---------------- host ----------------
extern "C" void kernel_launch(void* const* d_in, const int* in_sizes, int n_in,
                              void* d_out, int out_size, void* d_ws, size_t ws_size,
                              hipStream_t stream){
  const float* gaussians=(const float*)d_in[0];
  const float* visual=(const float*)d_in[1];
  const float* extr=(const float*)d_in[2];
  const float* intr=(const float*)d_in[3];
  const float* offs=(const float*)d_in[4];
  const float* pg_w=(const float*)d_in[5];
  const float* pg_b=(const float*)d_in[6];
  const float* pg_g=(const float*)d_in[7];
  const float* pg_bb=(const float*)d_in[8];
  const float* pv_w=(const float*)d_in[9];
  const float* pv_b=(const float*)d_in[10];
  const float* pv_g=(const float*)d_in[11];
  const float* pv_bb=(const float*)d_in[12];
  const float* ipw=(const float*)d_in[13];
  const float* ipb=(const float*)d_in[14];
  const float* ow=(const float*)d_in[15];
  const float* ob=(const float*)d_in[16];
  const float* dg=(const float*)d_in[17];
  const float* db=(const float*)d_in[18];
  const float* gate_w=(const float*)d_in[19];
  const float* gate_b=(const float*)d_in[20];
  const float* rw1=(const float*)d_in[21];
  const float* rb1=(const float*)d_in[22];
  const float* rlg=(const float*)d_in[23];
  const float* rlb=(const float*)d_in[24];
  const float* rw2=(const float*)d_in[25];
  const float* rb2=(const float*)d_in[26];
  const float* cent=(const float*)d_in[27];
  const float* cw=(const float*)d_in[28];
  const float* cb=(const float*)d_in[29];
  const float* bnw=(const float*)d_in[30];
  const float* bnb=(const float*)d_in[31];
  const float* blg=(const float*)d_in[32];
  const float* blb=(const float*)d_in[33];
  float* outp=(float*)d_out;
  float* ws=(float*)d_ws;

  // ws map (floats), high-water ~11.40M floats (~45.6MB); 48.2MB proven usable (r2)
  float* VF  = ws + 1048576;         // 0.5M
  float* GE  = ws + 1572864;         // 1M (live through vlad1)
  float* VE  = ws + 2621440;         // 1M (live through vlad1)
  unsigned short* GEb = (unsigned short*)(ws + 3670016);   // dead post-qkv -> PART0
  unsigned short* VEb = (unsigned short*)(ws + 4194304);
  unsigned* QKVu = (unsigned*)(ws + 4718592);              // 3M; dead post-flash
  float* CC  = ws + 4718592;         // 2M (post-flash)
  unsigned short* CCb = (unsigned short*)(ws + 6815744);   // 1M floats worth (post-flash)
  unsigned* OPARTw = (unsigned*)(ws + 7864320);            // 2M words; dead post-oproj
  float* FU  = ws + 8912896;         // 1M (written by gatef, after OPART dead)
  unsigned short* WB = (unsigned short*)(ws + 9961472);    // 94208 floats worth
  float* PARTD = ws + 10072064;      // 24576
  float* RW  = ws + 10096640;        // 16
  float* VLAD3 = ws + 10096656;      // 98304
  float* PART2 = ws + 10194960;      // 1M
  float* ASUMP3 = ws + 11243536;     // 24576
  float* LSUM  = ws + 11268112;      // 131072 (flash phase)
  float* RP    = ws + 11268112;      // 131072 (pre-flash; router consumes before flash writes LSUM)
  float* PART0 = ws + 3670016;       // over GEb/VEb (dead post-qkv)
  float* PART1 = ws + 7864320;       // over OPART (dead post-oproj)
  const unsigned short* QKVh = (const unsigned short*)QKVu;

  k_proj<<<2048,256,0,stream>>>(gaussians, visual, extr, intr, offs, VF);
  k_embed<<<8192,128,0,stream>>>(gaussians, VF, pg_w,pg_b,pg_g,pg_bb,
                                 pv_w,pv_b,pv_g,pv_bb, GE, VE, GEb, VEb);
  k_rpart<<<512,256,0,stream>>>(GE, VE, RP);
  k_router<<<4,128,0,stream>>>(RP, rw1,rb1,rlg,rlb,rw2,rb2, RW, outp+1024);
  k_wprep<<<736,256,0,stream>>>(ipw, ow, gate_w, cw, WB);

  const float qsc = 1.4426950408889634f * 0.17677669529663687f;  // log2e/sqrt(32)
  k_qkv<<<dim3(128,12),256,0,stream>>>(GEb, VEb, WB, ipb, QKVu, qsc);
  k_flash<<<dim3(32,4,16),256,0,stream>>>(QKVh, OPARTw, LSUM);
  k_oproj<<<dim3(128,2),256,0,stream>>>(OPARTw, LSUM, WB, ob, GE, VE, dg, db, CC, CCb);
  k_gatef<<<dim3(128,2),256,0,stream>>>(CCb, WB, gate_b, CC, FU);
  k_vlad1<<<dim3(32,4,3),256,0,stream>>>(GE, VE, FU, WB+163840, cb,
                                         PART0, PART1, PART2, ASUMP3);
  k_vagg2<<<dim3(64,4,3),128,0,stream>>>(PART0,PART1,PART2, ASUMP3, cent, VLAD3);
  k_desc<<<dim3(64,8,3),256,0,stream>>>(VLAD3, bnw, PARTD);
  k_final<<<4,256,0,stream>>>(PARTD, VLAD3, bnb, blg, blb, RW, outp);
}

// Round 18
// 192.911 us; speedup vs baseline: 1.1078x; 1.0587x over previous
//
#include <hip/hip_runtime.h>
#include <math.h>

// ---------------- types & helpers ----------------
typedef float f32x4 __attribute__((ext_vector_type(4)));
typedef short s16x8 __attribute__((ext_vector_type(8)));

#define DEV static __device__ __forceinline__

DEV float wsum(float v){
  #pragma unroll
  for(int m=1;m<64;m<<=1) v += __shfl_xor(v,m);
  return v;
}
template<int NW>
DEV float bsum(float v, float* s){
  v = wsum(v);
  int w = threadIdx.x>>6;
  if((threadIdx.x&63)==0) s[w]=v;
  __syncthreads();
  float r = 0.f;
  #pragma unroll
  for(int i=0;i<NW;++i) r += s[i];
  __syncthreads();
  return r;
}
DEV float xexp2(float x){
#if __has_builtin(__builtin_amdgcn_exp2f)
  return __builtin_amdgcn_exp2f(x);
#else
  return exp2f(x);
#endif
}
DEV unsigned pkbf(float lo, float hi){
  unsigned r;
  asm("v_cvt_pk_bf16_f32 %0, %1, %2" : "=v"(r) : "v"(lo), "v"(hi));
  return r;
}
DEV unsigned short bf16c(float v){ return (unsigned short)(pkbf(v, 0.f) & 0xffffu); }
DEV float ubf_lo(unsigned u){ unsigned b=(u&0xffffu)<<16; return __builtin_bit_cast(float,b); }
DEV float ubf_hi(unsigned u){ unsigned b=(u>>16)<<16;    return __builtin_bit_cast(float,b); }
union FR { unsigned u[4]; s16x8 v; uint4 q; };

DEV f32x4 MF(s16x8 a, s16x8 b, f32x4 c){
  return __builtin_amdgcn_mfma_f32_16x16x32_bf16(a, b, c, 0,0,0);
}

// async global -> LDS, 16B per lane; dest = wave-uniform base + lane*16
DEV void gl_lds16(const void* g, void* l){
  __builtin_amdgcn_global_load_lds(
    (const __attribute__((address_space(1))) void*)g,
    (__attribute__((address_space(3))) void*)l, 16, 0, 0);
}

// ---------------- feature-map transpose [BV,C,HW] -> [BV,HW,C] (LDS tiled) ----------------
__global__ __launch_bounds__(256) void k_trfm(const float* __restrict__ vf, float* __restrict__ fmT){
  int hc = blockIdx.x, bv = blockIdx.y, t = threadIdx.x;   // grid (16,16)
  __shared__ float ts[64][65];
  const float* src = vf + (size_t)bv*65536 + hc*64;
  int c = t>>2, q = t&3;
  #pragma unroll
  for(int i=0;i<4;++i){
    float4 v4 = *(const float4*)(src + (size_t)c*1024 + q*16 + i*4);
    ts[c][q*16+i*4+0]=v4.x; ts[c][q*16+i*4+1]=v4.y;
    ts[c][q*16+i*4+2]=v4.z; ts[c][q*16+i*4+3]=v4.w;
  }
  __syncthreads();
  int hw = t>>2;
  float* dst = fmT + ((size_t)bv*1024 + hc*64 + hw)*64 + q*16;
  #pragma unroll
  for(int i=0;i<4;++i){
    int cb = q*16 + i*4;
    float4 o4;
    o4.x = ts[cb+0][hw]; o4.y = ts[cb+1][hw]; o4.z = ts[cb+2][hw]; o4.w = ts[cb+3][hw];
    *(float4*)(dst + i*4) = o4;
  }
}

// ---------------- projection + bilinear sample -> vfeat [B,N,64] (4 rows/block) ----------------
__global__ __launch_bounds__(256) void k_proj(const float* __restrict__ gs, const float* __restrict__ fmT,
                       const float* __restrict__ E, const float* __restrict__ Kin,
                       const float* __restrict__ off, float* __restrict__ vfeat){
  int bn = blockIdx.x*4 + (threadIdx.x>>6); int b = bn>>11; int c = threadIdx.x&63;
  const float* g = gs + (size_t)bn*14;
  float px = g[0], py = g[1], pz = g[2];
  float ox = off[bn*2+0], oy = off[bn*2+1];
  float acc = 0.f, vsum = 0.f;
  for(int v=0; v<4; ++v){
    const float* e = E + ((b*4+v)*16);
    float cx = e[0]*px + e[1]*py + e[2]*pz + e[3];
    float cy = e[4]*px + e[5]*py + e[6]*pz + e[7];
    float cz = e[8]*px + e[9]*py + e[10]*pz + e[11];
    const float* kk = Kin + ((b*4+v)*9);
    float ux = kk[0]*cx + kk[1]*cy + kk[2]*cz;
    float uy = kk[3]*cx + kk[4]*cy + kk[5]*cz;
    float uz = kk[6]*cx + kk[7]*cy + kk[8]*cz;
    float dep = fmaxf(uz, 1e-6f);
    float gx = 2.f*(ux/dep)*(1.f/448.f) - 1.f + ox;
    float gy = 2.f*(uy/dep)*(1.f/448.f) - 1.f + oy;
    float valid = (uz > 0.1f && gx >= -1.f && gx <= 1.f && gy >= -1.f && gy <= 1.f) ? 1.f : 0.f;
    float x = (gx+1.f)*16.f - 0.5f;
    float y = (gy+1.f)*16.f - 0.5f;
    float x0 = floorf(x), y0 = floorf(y);
    const float* fbase = fmT + (size_t)(b*4+v)*65536 + c;
    float sv = 0.f;
    #pragma unroll
    for(int t=0;t<4;++t){
      float xi = x0 + (float)(t&1), yi = y0 + (float)(t>>1);
      float wgt = (1.f - fabsf(x-xi))*(1.f - fabsf(y-yi));
      bool vt = (xi>=0.f && xi<32.f && yi>=0.f && yi<32.f);
      int xc = (int)fminf(fmaxf(xi,0.f),31.f);
      int yc = (int)fminf(fmaxf(yi,0.f),31.f);
      float smp = fbase[(yc*32+xc)*64];
      sv += vt ? wgt*smp : 0.f;
    }
    acc += valid * sv;
    vsum += valid;
  }
  vfeat[(size_t)bn*64 + c] = acc / (vsum + 1e-8f);
}

// ---------------- embed: g_emb / v_emb = relu(LN(x@W^T+b)) + bf16 copies ----------------
__global__ void k_embed(const float* __restrict__ gs, const float* __restrict__ vfeat,
   const float* __restrict__ pg_w, const float* __restrict__ pg_b,
   const float* __restrict__ pg_g, const float* __restrict__ pg_bb,
   const float* __restrict__ pv_w, const float* __restrict__ pv_b,
   const float* __restrict__ pv_g, const float* __restrict__ pv_bb,
   float* __restrict__ gemb, float* __restrict__ vemb,
   unsigned short* __restrict__ gembb, unsigned short* __restrict__ vembb){
  __shared__ float xs[64]; __shared__ float gsr[14]; __shared__ float red[2];
  int row = blockIdx.x; int d = threadIdx.x;
  if(d<14) gsr[d] = gs[(size_t)row*14+d];
  if(d<64) xs[d] = vfeat[(size_t)row*64+d];
  __syncthreads();
  float a = pg_b[d];
  #pragma unroll
  for(int j=0;j<14;++j) a += gsr[j]*pg_w[d*14+j];
  float mu = bsum<2>(a, red)*(1.f/128.f);
  float df = a-mu;
  float var = bsum<2>(df*df, red)*(1.f/128.f);
  float y = fmaxf(df*rsqrtf(var+1e-5f)*pg_g[d] + pg_bb[d], 0.f);
  gemb[(size_t)row*128+d] = y;
  gembb[(size_t)row*128+d] = bf16c(y);
  float av = pv_b[d];
  #pragma unroll
  for(int j=0;j<64;++j) av += xs[j]*pv_w[d*64+j];
  mu = bsum<2>(av, red)*(1.f/128.f);
  df = av-mu;
  var = bsum<2>(df*df, red)*(1.f/128.f);
  y = fmaxf(df*rsqrtf(var+1e-5f)*pv_g[d] + pv_bb[d], 0.f);
  vemb[(size_t)row*128+d] = y;
  vembb[(size_t)row*128+d] = bf16c(y);
}

// ---------------- weights -> bf16 (ipw | ow | gate_w | cw) ----------------
__global__ void k_wprep(const float* __restrict__ ipw, const float* __restrict__ ow,
                        const float* __restrict__ gw, const float* __restrict__ cw,
                        unsigned short* __restrict__ WB){
  int i = blockIdx.x*256 + threadIdx.x;   // 188416
  if(i >= 188416) return;
  float v;
  if(i < 98304)       v = ipw[i];
  else if(i < 131072) v = ow[i-98304];
  else if(i < 163840) v = gw[i-131072];
  else                v = cw[i-163840];
  WB[i] = bf16c(v);
}

// ---------------- fused QKV projection -> flash layout (bf16) ----------------
__global__ __launch_bounds__(256) void k_qkv(const unsigned short* __restrict__ GEb,
    const unsigned short* __restrict__ VEb, const unsigned short* __restrict__ WB,
    const float* __restrict__ ipb, unsigned* __restrict__ QKVu, float qsc){
  int mt = blockIdx.x, y = blockIdx.y;
  int m = y/6, j6 = y%6, kind = j6>>1, n0 = (j6&1)*64;
  const unsigned short* A = (kind==0) ? (m?VEb:GEb) : (m?GEb:VEb);
  const unsigned short* W = WB + m*49152 + kind*16384;
  const float* bias = ipb + m*384 + kind*128;
  unsigned* outb = QKVu + (size_t)m*1572864 + (size_t)kind*524288;
  float scale = (kind==0)? qsc : 1.f;
  int m0 = mt*64;
  int wid=threadIdx.x>>6, lane=threadIdx.x&63, lr=lane&15, lg=lane>>4;
  const unsigned short* ap = A + (size_t)(m0+wid*16+lr)*128 + lg*8;
  f32x4 acc[4] = {{0,0,0,0},{0,0,0,0},{0,0,0,0},{0,0,0,0}};
  #pragma unroll
  for(int ks=0; ks<128; ks+=32){
    FR af; af.v = *(const s16x8*)(ap + ks);
    #pragma unroll
    for(int nt=0; nt<4; ++nt){
      FR bf; bf.v = *(const s16x8*)(W + (size_t)(n0+nt*16+lr)*128 + ks + lg*8);
      acc[nt] = MF(af.v, bf.v, acc[nt]);
    }
  }
  __shared__ float xs[64][65];
  #pragma unroll
  for(int nt=0; nt<4; ++nt){
    float bv = bias[n0+nt*16+lr];
    #pragma unroll
    for(int r=0;r<4;++r) xs[wid*16+lg*4+r][nt*16+lr] = (acc[nt][r]+bv)*scale;
  }
  __syncthreads();
  if(kind<2){
    int i = threadIdx.x>>2, s = threadIdx.x&3;
    int gr = m0 + i, b = gr>>11, nn = gr&2047;
    int j0 = n0 + s*16, h = j0>>5, d0 = j0&31;
    unsigned w[8];
    #pragma unroll
    for(int p=0;p<8;++p) w[p] = pkbf(xs[i][s*16+2*p], xs[i][s*16+2*p+1]);
    unsigned* dst = outb + ((size_t)(b*4+h)*2048+nn)*16 + (d0>>1);
    uint4 u0; u0.x=w[0];u0.y=w[1];u0.z=w[2];u0.w=w[3];
    uint4 u1; u1.x=w[4];u1.y=w[5];u1.z=w[6];u1.w=w[7];
    *(uint4*)dst = u0; *(uint4*)(dst+4) = u1;
  } else {
    int c = threadIdx.x>>2, rs = threadIdx.x&3;
    int j = n0 + c, h = j>>5, d = j&31;
    int b = m0>>11, nn0 = m0&2047;
    unsigned w[8];
    #pragma unroll
    for(int p=0;p<8;++p) w[p] = pkbf(xs[rs*16+2*p][c], xs[rs*16+2*p+1][c]);
    unsigned* dst = outb + (size_t)(b*4+h)*32768 + (size_t)d*1024 + ((nn0+rs*16)>>1);
    uint4 u0; u0.x=w[0];u0.y=w[1];u0.z=w[2];u0.w=w[3];
    uint4 u1; u1.x=w[4];u1.y=w[5];u1.z=w[6];u1.w=w[7];
    *(uint4*)dst = u0; *(uint4*)(dst+4) = u1;
  }
}

// ---------------- MFMA bf16 flash attention v9: LDS staging, K+V XOR-swizzled ----------------
__global__ __launch_bounds__(256) void k_flash(const unsigned short* __restrict__ QKV,
    unsigned* __restrict__ OPARTw, float* __restrict__ LSUM){
  int qt = blockIdx.x, h = blockIdx.y, z = blockIdx.z;   // grid (32,4,16)
  int mb = z&7, split = z>>3;
  int m = mb>>2, b = mb&3;
  const unsigned short* base = QKV + (size_t)m*3145728;
  const unsigned short* qp = base + (size_t)(b*4+h)*65536;
  const unsigned short* kp = qp + 1048576;
  const unsigned short* vp = qp + 2097152;
  int tid=threadIdx.x, wid=tid>>6, lane=tid&63, lr=lane&15, lg=lane>>4;
  __shared__ unsigned short KT[2][2048];
  __shared__ unsigned short VT[2][2048];
  __shared__ unsigned Ps[4][16][33];
  int q0 = qt*64 + wid*16;
  int kbase = split*1024;
  FR qf; qf.v = *(const s16x8*)(qp + (size_t)(q0+lr)*32 + lg*8);
  const f32x4 zz = {0.f,0.f,0.f,0.f};
  f32x4 o0g = zz, o1g = zz;
  float lrun = 0.f;
  unsigned* prow = &Ps[wid][lr][0];
  int kr = wid*16 + (lane>>2);
  int kscol = (((lane&3)<<3) ^ (((lane>>3)&3)<<3));
  const unsigned short* ksrc0 = kp + (size_t)(kbase + kr)*32 + kscol;
  int vrow = wid*8 + (lane>>3);
  int vscol = 8*((lane&7) ^ (lane>>3));
  const unsigned short* vsrc0 = vp + (size_t)vrow*2048 + kbase + vscol;
  int kkey = ((lr>>1)&3)<<3;
  int ko = lr*32 + ((lg*8) ^ kkey);
  int sw = (lr&7)*8;
  int vo0 = lr*64 + ((lg*8) ^ sw);
  int vo2 = lr*64 + ((32+lg*8) ^ sw);
  gl_lds16(ksrc0, &KT[0][wid*512]);
  gl_lds16(vsrc0, &VT[0][wid*512]);
  __syncthreads();
  int buf = 0;
  for(int t=0; t<16; ++t){
    int tn = (t+1)&15;
    gl_lds16(ksrc0 + (size_t)tn*2048, &KT[buf^1][wid*512]);
    gl_lds16(vsrc0 + tn*64,           &VT[buf^1][wid*512]);
    const unsigned short* Ktb = &KT[buf][0];
    const unsigned short* Vtb = &VT[buf][0];
    FR k0,k1,k2,k3;
    k0.v = *(const s16x8*)(Ktb + ko);
    k1.v = *(const s16x8*)(Ktb +  512 + ko);
    k2.v = *(const s16x8*)(Ktb + 1024 + ko);
    k3.v = *(const s16x8*)(Ktb + 1536 + ko);
    f32x4 s0 = MF(k0.v, qf.v, zz);
    f32x4 s1 = MF(k1.v, qf.v, zz);
    f32x4 s2 = MF(k2.v, qf.v, zz);
    f32x4 s3 = MF(k3.v, qf.v, zz);
    float p0[4],p1[4],p2[4],p3[4]; float ps=0.f;
    #pragma unroll
    for(int r=0;r<4;++r){
      p0[r]=xexp2(s0[r]); p1[r]=xexp2(s1[r]);
      p2[r]=xexp2(s2[r]); p3[r]=xexp2(s3[r]);
      ps += p0[r]+p1[r]+p2[r]+p3[r];
    }
    lrun += ps;
    asm volatile("" ::: "memory");
    prow[   lg*2+0]=pkbf(p0[0],p0[1]); prow[   lg*2+1]=pkbf(p0[2],p0[3]);
    prow[ 8+lg*2+0]=pkbf(p1[0],p1[1]); prow[ 8+lg*2+1]=pkbf(p1[2],p1[3]);
    prow[16+lg*2+0]=pkbf(p2[0],p2[1]); prow[16+lg*2+1]=pkbf(p2[2],p2[3]);
    prow[24+lg*2+0]=pkbf(p3[0],p3[1]); prow[24+lg*2+1]=pkbf(p3[2],p3[3]);
    asm volatile("" ::: "memory");
    FR pf0, pf1;
    #pragma unroll
    for(int i=0;i<4;++i){ pf0.u[i]=prow[lg*4+i]; pf1.u[i]=prow[16+lg*4+i]; }
    FR v0,v1,v2,v3;
    v0.v = *(const s16x8*)(Vtb + vo0);
    v1.v = *(const s16x8*)(Vtb + 1024 + vo0);
    v2.v = *(const s16x8*)(Vtb + vo2);
    v3.v = *(const s16x8*)(Vtb + 1024 + vo2);
    o0g = MF(v0.v, pf0.v, o0g);
    o1g = MF(v1.v, pf0.v, o1g);
    o0g = MF(v2.v, pf1.v, o0g);
    o1g = MF(v3.v, pf1.v, o1g);
    __syncthreads();
    buf ^= 1;
  }
  lrun += __shfl_xor(lrun,16); lrun += __shfl_xor(lrun,32);
  unsigned w00=pkbf(o0g[0],o0g[1]), w01=pkbf(o0g[2],o0g[3]);
  unsigned w10=pkbf(o1g[0],o1g[1]), w11=pkbf(o1g[2],o1g[3]);
  unsigned* op = OPARTw + ((size_t)(split*2+m)*8192 + (size_t)(b*2048+q0+lr))*64 + h*16 + lg*2;
  op[0]=w00; op[1]=w01; op[8]=w10; op[9]=w11;
  if(lg==0) LSUM[((size_t)(split*2+m)*16 + b*4+h)*2048 + q0+lr] = lrun;
}

// ---------------- fused split-K merge + out-proj GEMM + bias + residual + LN ----------------
__global__ __launch_bounds__(256) void k_oproj(const unsigned* __restrict__ OPARTw,
    const float* __restrict__ LSUM,
    const unsigned short* __restrict__ WB, const float* __restrict__ ob,
    const float* __restrict__ GE, const float* __restrict__ VE,
    const float* __restrict__ dg, const float* __restrict__ db,
    float* __restrict__ CC, unsigned short* __restrict__ CCb){
  int mt = blockIdx.x, m = blockIdx.y;
  int m0 = mt*64;
  const unsigned short* W = WB + 98304 + m*16384;
  const float* bias = ob + m*128;
  const float* R = m ? VE : GE;
  const float* gamma = dg + m*128;
  const float* beta  = db + m*128;
  int wid=threadIdx.x>>6, lane=threadIdx.x&63, lr=lane&15, lg=lane>>4;
  int gr = m0 + wid*16 + lr;
  int b2 = gr>>11, nn = gr&2047;
  float invh[4];
  #pragma unroll
  for(int h=0;h<4;++h){
    float l0 = LSUM[((size_t)(m*16) + b2*4+h)*2048 + nn];
    float l1 = LSUM[((size_t)((2+m)*16) + b2*4+h)*2048 + nn];
    invh[h] = 1.f/(l0+l1);
  }
  const unsigned* a0 = OPARTw + ((size_t)m*8192 + gr)*64 + lg*4;
  const unsigned* a1 = OPARTw + ((size_t)(2+m)*8192 + gr)*64 + lg*4;
  f32x4 acc[8] = {};
  #pragma unroll
  for(int ks=0; ks<4; ++ks){
    uint4 u0 = *(const uint4*)(a0 + ks*16);
    uint4 u1 = *(const uint4*)(a1 + ks*16);
    float sc = invh[ks];
    FR af;
    af.u[0] = pkbf((ubf_lo(u0.x)+ubf_lo(u1.x))*sc, (ubf_hi(u0.x)+ubf_hi(u1.x))*sc);
    af.u[1] = pkbf((ubf_lo(u0.y)+ubf_lo(u1.y))*sc, (ubf_hi(u0.y)+ubf_hi(u1.y))*sc);
    af.u[2] = pkbf((ubf_lo(u0.z)+ubf_lo(u1.z))*sc, (ubf_hi(u0.z)+ubf_hi(u1.z))*sc);
    af.u[3] = pkbf((ubf_lo(u0.w)+ubf_lo(u1.w))*sc, (ubf_hi(u0.w)+ubf_hi(u1.w))*sc);
    #pragma unroll
    for(int nt=0; nt<8; ++nt){
      FR bf; bf.v = *(const s16x8*)(W + (size_t)(nt*16+lr)*128 + ks*32 + lg*8);
      acc[nt] = MF(af.v, bf.v, acc[nt]);
    }
  }
  __shared__ float xs[64][129];
  __shared__ float mus[64], rss[64];
  #pragma unroll
  for(int nt=0; nt<8; ++nt){
    float bv = bias[nt*16+lr];
    #pragma unroll
    for(int r=0;r<4;++r){
      int row = wid*16+lg*4+r;
      xs[row][nt*16+lr] = acc[nt][r] + bv + R[(size_t)(m0+row)*128 + nt*16+lr];
    }
  }
  __syncthreads();
  if(threadIdx.x < 64){
    int row = threadIdx.x;
    float s=0.f, s2=0.f;
    #pragma unroll 8
    for(int c=0;c<128;++c){ float x = xs[row][c]; s += x; s2 += x*x; }
    float mu = s*(1.f/128.f);
    float var = fmaxf(s2*(1.f/128.f) - mu*mu, 0.f);
    mus[row] = mu; rss[row] = rsqrtf(var + 1e-5f);
  }
  __syncthreads();
  int row = threadIdx.x>>2, cs = (threadIdx.x&3)*32;
  float mu = mus[row], rs = rss[row];
  size_t obase = (size_t)(m0+row)*256 + m*128;
  #pragma unroll 8
  for(int c=cs;c<cs+32;++c){
    float y = (xs[row][c]-mu)*rs*gamma[c] + beta[c];
    CC [obase + c] = y;
    CCb[obase + c] = bf16c(y);
  }
}

// ---------------- fused gate GEMM + sigmoid + mix -> FU ----------------
__global__ __launch_bounds__(256) void k_gatef(const unsigned short* __restrict__ CCb,
    const unsigned short* __restrict__ WB, const float* __restrict__ gate_b,
    const float* __restrict__ CC, float* __restrict__ FU){
  int mt = blockIdx.x;
  int m0 = mt*64;
  const unsigned short* W = WB + 131072;
  int wid=threadIdx.x>>6, lane=threadIdx.x&63, lr=lane&15, lg=lane>>4;
  const unsigned short* ap = CCb + (size_t)(m0+wid*16+lr)*256 + lg*8;
  f32x4 acc[8] = {};
  #pragma unroll
  for(int ks=0; ks<256; ks+=32){
    FR af; af.v = *(const s16x8*)(ap + ks);
    #pragma unroll
    for(int nt=0; nt<8; ++nt){
      FR bf; bf.v = *(const s16x8*)(W + (size_t)(nt*16+lr)*256 + ks + lg*8);
      acc[nt] = MF(af.v, bf.v, acc[nt]);
    }
  }
  #pragma unroll
  for(int nt=0; nt<8; ++nt){
    int col = nt*16+lr;
    float bv = gate_b[col];
    #pragma unroll
    for(int r=0;r<4;++r){
      int row = m0 + wid*16+lg*4+r;
      float gv = 1.f/(1.f+__expf(-(acc[nt][r]+bv)));
      FU[(size_t)row*128 + col] = CC[(size_t)row*256 + col]*gv
                                + CC[(size_t)row*256 + 128 + col]*(1.f-gv);
    }
  }
}

// ---------------- router ----------------
__global__ void k_rpart(const float* __restrict__ gemb, const float* __restrict__ vemb,
                        float* __restrict__ part){
  int blk = blockIdx.x;  // 64 = b(4) x ch(16), 128 rows each
  int b = blk>>4, ch = blk&15, t = threadIdx.x;
  const float* src = (t<128)? gemb : vemb;
  int d = t&127;
  float s=0.f;
  int n0 = ch*128;
  for(int n=0;n<128;++n) s += src[((size_t)(b*2048+n0+n))*128 + d];
  part[(size_t)blk*256 + t] = s;
}
__global__ void k_router(const float* __restrict__ part, const float* __restrict__ w1,
     const float* __restrict__ b1, const float* __restrict__ lg, const float* __restrict__ lb,
     const float* __restrict__ w2, const float* __restrict__ b2,
     float* __restrict__ rw, float* __restrict__ outrw){
  __shared__ float ri[256]; __shared__ float red[2];
  int b = blockIdx.x, t = threadIdx.x;  // 128 threads
  for(int j=t; j<256; j+=128){
    float s=0.f;
    for(int c=0;c<16;++c) s += part[(size_t)(b*16+c)*256 + j];
    ri[j] = s*(1.f/2048.f);
  }
  __syncthreads();
  float a = b1[t];
  for(int j=0;j<256;++j) a += ri[j]*w1[t*256+j];
  float mu = bsum<2>(a,red)*(1.f/128.f);
  float df = a-mu;
  float var = bsum<2>(df*df,red)*(1.f/128.f);
  float hv = fmaxf(df*rsqrtf(var+1e-5f)*lg[t]+lb[t], 0.f);
  float l0 = bsum<2>(hv*w2[t],red);
  float l1 = bsum<2>(hv*w2[128+t],red);
  float l2 = bsum<2>(hv*w2[256+t],red);
  if(t==0){
    l0+=b2[0]; l1+=b2[1]; l2+=b2[2];
    float mx = fmaxf(l0,fmaxf(l1,l2));
    float e0=__expf(l0-mx), e1=__expf(l1-mx), e2=__expf(l2-mx);
    float s=e0+e1+e2;
    rw[b*3+0]=e0/s; rw[b*3+1]=e1/s; rw[b*3+2]=e2/s;
    outrw[b*3+0]=e0/s; outrw[b*3+1]=e1/s; outrw[b*3+2]=e2/s;
  }
}

// ---------------- fused NetVLAD assign+aggregate (MFMA), per 64-row chunk ----------------
__global__ __launch_bounds__(256) void k_vlad1(
      const float* __restrict__ GE, const float* __restrict__ VE, const float* __restrict__ FU,
      const unsigned short* __restrict__ WBcw, const float* __restrict__ cbp,
      float* __restrict__ p0, float* __restrict__ p1, float* __restrict__ p2,
      float* __restrict__ asump){
  int ch = blockIdx.x, b = blockIdx.y, z = blockIdx.z;
  const float* feat = (z==0)?GE:((z==1)?VE:FU);
  const unsigned short* cwb = WBcw + z*8192;
  const float* cb = cbp + z*64;
  float* part = (z==0)?p0:((z==1)?p1:p2);
  float* asu = asump + z*8192;
  int t = threadIdx.x;
  __shared__ unsigned xnbu[64*36];
  __shared__ unsigned short xnbT[128*72];
  __shared__ unsigned abTu[64*36];
  int nbase = b*2048 + ch*64;
  {
    int r = t>>2, q = t&3;
    const float* frow = feat + (size_t)(nbase + r)*128 + q*32;
    float v[32]; float ssq = 0.f;
    #pragma unroll
    for(int i=0;i<8;++i){
      float4 f4 = *(const float4*)(frow + i*4);
      v[i*4+0]=f4.x; v[i*4+1]=f4.y; v[i*4+2]=f4.z; v[i*4+3]=f4.w;
      ssq += f4.x*f4.x+f4.y*f4.y+f4.z*f4.z+f4.w*f4.w;
    }
    ssq += __shfl_xor(ssq,1); ssq += __shfl_xor(ssq,2);
    float inv = 1.f/fmaxf(sqrtf(ssq),1e-12f);
    #pragma unroll
    for(int i=0;i<16;++i)
      xnbu[r*36 + q*8 + i] = pkbf(v[2*i]*inv, v[2*i+1]*inv);
    #pragma unroll
    for(int j=0;j<32;++j)
      xnbT[(q*32+j)*72 + r] = bf16c(v[j]*inv);
  }
  __syncthreads();
  int w = t>>6, lane = t&63, lr = lane&15, lg = lane>>4;
  {
    f32x4 acc[4] = {};
    #pragma unroll
    for(int ks=0; ks<4; ++ks){
      FR af; af.q = *(const uint4*)&xnbu[(w*16+lr)*36 + ks*16 + lg*4];
      #pragma unroll
      for(int nt=0; nt<4; ++nt){
        FR bf; bf.v = *(const s16x8*)(cwb + (size_t)(nt*16+lr)*128 + ks*32 + lg*8);
        acc[nt] = MF(af.v, bf.v, acc[nt]);
      }
    }
    float p[4][4]; float srow[4] = {0.f,0.f,0.f,0.f};
    #pragma unroll
    for(int nt=0;nt<4;++nt){
      float cbv = cb[nt*16+lr];
      #pragma unroll
      for(int rr=0;rr<4;++rr){
        p[nt][rr] = __expf(acc[nt][rr] + cbv);
        srow[rr] += p[nt][rr];
      }
    }
    #pragma unroll
    for(int rr=0;rr<4;++rr){
      float s = srow[rr];
      s += __shfl_xor(s,1); s += __shfl_xor(s,2); s += __shfl_xor(s,4); s += __shfl_xor(s,8);
      srow[rr] = 1.f/s;
    }
    #pragma unroll
    for(int nt=0;nt<4;++nt){
      int k = nt*16+lr;
      abTu[k*36 + w*8 + lg*2 + 0] = pkbf(p[nt][0]*srow[0], p[nt][1]*srow[1]);
      abTu[k*36 + w*8 + lg*2 + 1] = pkbf(p[nt][2]*srow[2], p[nt][3]*srow[3]);
    }
  }
  __syncthreads();
  {
    f32x4 acc[8] = {};
    #pragma unroll
    for(int ns=0; ns<2; ++ns){
      FR af; af.q = *(const uint4*)&abTu[(w*16+lr)*36 + ns*16 + lg*4];
      #pragma unroll
      for(int nt=0; nt<8; ++nt){
        FR bf; bf.v = *(const s16x8*)&xnbT[(nt*16+lr)*72 + ns*32 + lg*8];
        acc[nt] = MF(af.v, bf.v, acc[nt]);
      }
    }
    size_t pb = ((size_t)(b*32+ch)*64);
    #pragma unroll
    for(int nt=0; nt<8; ++nt){
      #pragma unroll
      for(int rr=0; rr<4; ++rr){
        int k = w*16+lg*4+rr;
        part[(pb + k)*128 + nt*16+lr] = acc[nt][rr];
      }
    }
  }
  if(t<64){
    float s = 0.f;
    #pragma unroll
    for(int i=0;i<32;++i){
      unsigned u = abTu[t*36+i];
      s += ubf_lo(u) + ubf_hi(u);
    }
    asu[((size_t)(b*32+ch))*64 + t] = s;
  }
}

// ---- vlad stage 2 (z-batched): reduce partials, subtract centers, l2n ----
__global__ void k_vagg2(
      const float* __restrict__ p0, const float* __restrict__ p1, const float* __restrict__ p2,
      const float* __restrict__ asump, const float* __restrict__ cent, float* __restrict__ vlad3){
  int k = blockIdx.x, b = blockIdx.y, z = blockIdx.z;   // grid (64,4,3), 128 thr
  const float* part = (z==0)?p0:((z==1)?p1:p2);
  const float* asu = asump + z*8192;
  const float* centp = cent + (size_t)z*8192;
  float* vlad = vlad3 + z*32768;
  int t = threadIdx.x;
  __shared__ float red[2];
  float v = 0.f;
  const float* pp = part + (((size_t)b*32)*64 + k)*128 + t;
  for(int ch=0; ch<32; ++ch) v += pp[(size_t)ch*8192];
  float as = 0.f;
  const float* ap = asu + (size_t)b*2048 + k;
  for(int ch=0; ch<32; ++ch) as += ap[(size_t)ch*64];
  v -= as * centp[(size_t)k*128 + t];
  float ssq = bsum<2>(v*v, red);
  float inv = 1.f/fmaxf(sqrtf(ssq),1e-12f);
  vlad[((size_t)b*64+k)*128+t] = v*inv;
}

// ---- descriptor GEMV (z-batched, LDS-staged) ----
__global__ __launch_bounds__(256) void k_desc(const float* __restrict__ vlad3,
      const float* __restrict__ bnw, const float* __restrict__ bnb, float* __restrict__ DT){
  int jg = blockIdx.x, b = blockIdx.y, z = blockIdx.z;   // grid (64,4,3)
  const float* vlad = vlad3 + z*32768;
  const float* bw = bnw + (size_t)z*2097152;
  const float* bb = bnb + z*256;
  float* dtmp = DT + z*1024;
  int t = threadIdx.x;
  __shared__ float fl[8192]; __shared__ float red[4];
  const float4* src = (const float4*)(vlad + (size_t)b*8192);
  float4* fl4 = (float4*)fl;
  float ssq = 0.f;
  #pragma unroll
  for(int i=0;i<8;++i){
    float4 vv = src[t + i*256]; fl4[t+i*256]=vv;
    ssq += vv.x*vv.x+vv.y*vv.y+vv.z*vv.z+vv.w*vv.w;
  }
  ssq = bsum<4>(ssq, red);
  float inv = 1.f/fmaxf(sqrtf(ssq),1e-12f);
  for(int jj=0;jj<4;++jj){
    int j = jg*4 + jj;
    const float4* wp = (const float4*)(bw + (size_t)j*8192);
    float s = 0.f;
    #pragma unroll
    for(int i=0;i<8;++i){
      int f = t + i*256;
      float4 w4 = wp[f]; float4 x4 = fl4[f];
      s += w4.x*x4.x+w4.y*x4.y+w4.z*x4.z+w4.w*x4.w;
    }
    s = bsum<4>(s, red);
    if(t==0) dtmp[(size_t)b*256 + j] = s*inv + bb[j];
  }
}

// ---------------- final ----------------
__global__ void k_final(const float* __restrict__ dtmp, const float* __restrict__ lg,
      const float* __restrict__ lb, const float* __restrict__ rw, float* __restrict__ outp){
  __shared__ float red[4];
  int b = blockIdx.x, t = threadIdx.x;  // 256
  float acc = 0.f;
  for(int i=0;i<3;++i){
    float x = dtmp[(size_t)(i*4+b)*256 + t];
    float mu = bsum<4>(x,red)*(1.f/256.f);
    float df = x-mu;
    float var = bsum<4>(df*df,red)*(1.f/256.f);
    float y = df*rsqrtf(var+1e-5f)*lg[i*256+t]+lb[i*256+t];
    float n2 = bsum<4>(y*y,red);
    y = y / fmaxf(sqrtf(n2),1e-12f);
    acc += rw[b*3+i]*y;
  }
  float n2 = bsum<4>(acc*acc,red);
  outp[(size_t)b*256+t] = acc/fmaxf(sqrtf(n2),1e-12f);
}

// ---------------- host ----------------
extern "C" void kernel_launch(void* const* d_in, const int* in_sizes, int n_in,
                              void* d_out, int out_size, void* d_ws, size_t ws_size,
                              hipStream_t stream){
  const float* gaussians=(const float*)d_in[0];
  const float* visual=(const float*)d_in[1];
  const float* extr=(const float*)d_in[2];
  const float* intr=(const float*)d_in[3];
  const float* offs=(const float*)d_in[4];
  const float* pg_w=(const float*)d_in[5];
  const float* pg_b=(const float*)d_in[6];
  const float* pg_g=(const float*)d_in[7];
  const float* pg_bb=(const float*)d_in[8];
  const float* pv_w=(const float*)d_in[9];
  const float* pv_b=(const float*)d_in[10];
  const float* pv_g=(const float*)d_in[11];
  const float* pv_bb=(const float*)d_in[12];
  const float* ipw=(const float*)d_in[13];
  const float* ipb=(const float*)d_in[14];
  const float* ow=(const float*)d_in[15];
  const float* ob=(const float*)d_in[16];
  const float* dg=(const float*)d_in[17];
  const float* db=(const float*)d_in[18];
  const float* gate_w=(const float*)d_in[19];
  const float* gate_b=(const float*)d_in[20];
  const float* rw1=(const float*)d_in[21];
  const float* rb1=(const float*)d_in[22];
  const float* rlg=(const float*)d_in[23];
  const float* rlb=(const float*)d_in[24];
  const float* rw2=(const float*)d_in[25];
  const float* rb2=(const float*)d_in[26];
  const float* cent=(const float*)d_in[27];
  const float* cw=(const float*)d_in[28];
  const float* cb=(const float*)d_in[29];
  const float* bnw=(const float*)d_in[30];
  const float* bnb=(const float*)d_in[31];
  const float* blg=(const float*)d_in[32];
  const float* blb=(const float*)d_in[33];
  float* outp=(float*)d_out;
  float* ws=(float*)d_ws;

  // ws map (floats), high-water ~11.38M floats (~45.5MB); 48.2MB proven usable (r2)
  float* FMT = ws + 0;               // 1M (phase1)
  float* VF  = ws + 1048576;         // 0.5M
  float* GE  = ws + 1572864;         // 1M (live through vlad1)
  float* VE  = ws + 2621440;         // 1M (live through vlad1)
  unsigned short* GEb = (unsigned short*)(ws + 3670016);   // dead post-qkv -> PART0
  unsigned short* VEb = (unsigned short*)(ws + 4194304);
  unsigned* QKVu = (unsigned*)(ws + 4718592);              // 3M; dead post-flash
  float* CC  = ws + 4718592;         // 2M (post-flash)
  unsigned short* CCb = (unsigned short*)(ws + 6815744);   // 1M floats worth (post-flash)
  unsigned* OPARTw = (unsigned*)(ws + 7864320);            // 2M words; dead post-oproj
  float* FU  = ws + 8912896;         // 1M (written by gatef, after OPART dead)
  unsigned short* WB = (unsigned short*)(ws + 9961472);    // 94208 floats worth
  float* RP  = ws + 10055680;        // 16384
  float* DT  = ws + 10072064;        // 3072
  float* RW  = ws + 10075136;        // 16
  float* VLAD3 = ws + 10075152;      // 98304
  float* PART2 = ws + 10173456;      // 1M
  float* ASUMP3 = ws + 11222032;     // 24576
  float* LSUM  = ws + 11246608;      // 131072 (flash phase)
  float* PART0 = ws + 3670016;       // over GEb/VEb (dead post-qkv)
  float* PART1 = ws + 7864320;       // over OPART (dead post-oproj)
  const unsigned short* QKVh = (const unsigned short*)QKVu;

  k_trfm<<<dim3(16,16),256,0,stream>>>(visual, FMT);
  k_proj<<<2048,256,0,stream>>>(gaussians, FMT, extr, intr, offs, VF);
  k_embed<<<8192,128,0,stream>>>(gaussians, VF, pg_w,pg_b,pg_g,pg_bb,
                                 pv_w,pv_b,pv_g,pv_bb, GE, VE, GEb, VEb);
  k_rpart<<<64,256,0,stream>>>(GE, VE, RP);
  k_router<<<4,128,0,stream>>>(RP, rw1,rb1,rlg,rlb,rw2,rb2, RW, outp+1024);
  k_wprep<<<736,256,0,stream>>>(ipw, ow, gate_w, cw, WB);

  const float qsc = 1.4426950408889634f * 0.17677669529663687f;  // log2e/sqrt(32)
  k_qkv<<<dim3(128,12),256,0,stream>>>(GEb, VEb, WB, ipb, QKVu, qsc);
  k_flash<<<dim3(32,4,16),256,0,stream>>>(QKVh, OPARTw, LSUM);
  k_oproj<<<dim3(128,2),256,0,stream>>>(OPARTw, LSUM, WB, ob, GE, VE, dg, db, CC, CCb);
  k_gatef<<<128,256,0,stream>>>(CCb, WB, gate_b, CC, FU);
  k_vlad1<<<dim3(32,4,3),256,0,stream>>>(GE, VE, FU, WB+163840, cb,
                                         PART0, PART1, PART2, ASUMP3);
  k_vagg2<<<dim3(64,4,3),128,0,stream>>>(PART0,PART1,PART2, ASUMP3, cent, VLAD3);
  k_desc<<<dim3(64,4,3),256,0,stream>>>(VLAD3, bnw, bnb, DT);
  k_final<<<4,256,0,stream>>>(DT, blg, blb, RW, outp);
}

// Round 19
// 191.448 us; speedup vs baseline: 1.1163x; 1.0076x over previous
//
#include <hip/hip_runtime.h>
#include <math.h>

// ---------------- types & helpers ----------------
typedef float f32x4 __attribute__((ext_vector_type(4)));
typedef short s16x8 __attribute__((ext_vector_type(8)));

#define DEV static __device__ __forceinline__

DEV float wsum(float v){
  #pragma unroll
  for(int m=1;m<64;m<<=1) v += __shfl_xor(v,m);
  return v;
}
template<int NW>
DEV float bsum(float v, float* s){
  v = wsum(v);
  int w = threadIdx.x>>6;
  if((threadIdx.x&63)==0) s[w]=v;
  __syncthreads();
  float r = 0.f;
  #pragma unroll
  for(int i=0;i<NW;++i) r += s[i];
  __syncthreads();
  return r;
}
DEV float xexp2(float x){
#if __has_builtin(__builtin_amdgcn_exp2f)
  return __builtin_amdgcn_exp2f(x);
#else
  return exp2f(x);
#endif
}
DEV unsigned pkbf(float lo, float hi){
  unsigned r;
  asm("v_cvt_pk_bf16_f32 %0, %1, %2" : "=v"(r) : "v"(lo), "v"(hi));
  return r;
}
DEV unsigned short bf16c(float v){ return (unsigned short)(pkbf(v, 0.f) & 0xffffu); }
DEV float ubf_lo(unsigned u){ unsigned b=(u&0xffffu)<<16; return __builtin_bit_cast(float,b); }
DEV float ubf_hi(unsigned u){ unsigned b=(u>>16)<<16;    return __builtin_bit_cast(float,b); }
union FR { unsigned u[4]; s16x8 v; uint4 q; };

DEV f32x4 MF(s16x8 a, s16x8 b, f32x4 c){
  return __builtin_amdgcn_mfma_f32_16x16x32_bf16(a, b, c, 0,0,0);
}

// async global -> LDS, 16B per lane; dest = wave-uniform base + lane*16
DEV void gl_lds16(const void* g, void* l){
  __builtin_amdgcn_global_load_lds(
    (const __attribute__((address_space(1))) void*)g,
    (__attribute__((address_space(3))) void*)l, 16, 0, 0);
}

// ---------------- merged prep: fm transpose (blocks 0..255) + weights->bf16 (blocks 256..991) ----------------
__global__ __launch_bounds__(256) void k_prep(const float* __restrict__ vf, float* __restrict__ fmT,
                        const float* __restrict__ ipw, const float* __restrict__ ow,
                        const float* __restrict__ gw, const float* __restrict__ cw,
                        unsigned short* __restrict__ WB){
  int blk = blockIdx.x;
  __shared__ float ts[64][65];
  if(blk < 256){
    int hc = blk & 15, bv = blk >> 4, t = threadIdx.x;
    const float* src = vf + (size_t)bv*65536 + hc*64;
    int c = t>>2, q = t&3;
    #pragma unroll
    for(int i=0;i<4;++i){
      float4 v4 = *(const float4*)(src + (size_t)c*1024 + q*16 + i*4);
      ts[c][q*16+i*4+0]=v4.x; ts[c][q*16+i*4+1]=v4.y;
      ts[c][q*16+i*4+2]=v4.z; ts[c][q*16+i*4+3]=v4.w;
    }
    __syncthreads();
    int hw = t>>2;
    float* dst = fmT + ((size_t)bv*1024 + hc*64 + hw)*64 + q*16;
    #pragma unroll
    for(int i=0;i<4;++i){
      int cb = q*16 + i*4;
      float4 o4;
      o4.x = ts[cb+0][hw]; o4.y = ts[cb+1][hw]; o4.z = ts[cb+2][hw]; o4.w = ts[cb+3][hw];
      *(float4*)(dst + i*4) = o4;
    }
  } else {
    int i = (blk-256)*256 + threadIdx.x;   // 0..188415
    if(i < 188416){
      float v;
      if(i < 98304)       v = ipw[i];
      else if(i < 131072) v = ow[i-98304];
      else if(i < 163840) v = gw[i-131072];
      else                v = cw[i-163840];
      WB[i] = bf16c(v);
    }
  }
}

// ---------------- projection + bilinear sample -> vfeat [B,N,64] (4 rows/block) ----------------
__global__ __launch_bounds__(256) void k_proj(const float* __restrict__ gs, const float* __restrict__ fmT,
                       const float* __restrict__ E, const float* __restrict__ Kin,
                       const float* __restrict__ off, float* __restrict__ vfeat){
  int bn = blockIdx.x*4 + (threadIdx.x>>6); int b = bn>>11; int c = threadIdx.x&63;
  const float* g = gs + (size_t)bn*14;
  float px = g[0], py = g[1], pz = g[2];
  float ox = off[bn*2+0], oy = off[bn*2+1];
  float acc = 0.f, vsum = 0.f;
  for(int v=0; v<4; ++v){
    const float* e = E + ((b*4+v)*16);
    float cx = e[0]*px + e[1]*py + e[2]*pz + e[3];
    float cy = e[4]*px + e[5]*py + e[6]*pz + e[7];
    float cz = e[8]*px + e[9]*py + e[10]*pz + e[11];
    const float* kk = Kin + ((b*4+v)*9);
    float ux = kk[0]*cx + kk[1]*cy + kk[2]*cz;
    float uy = kk[3]*cx + kk[4]*cy + kk[5]*cz;
    float uz = kk[6]*cx + kk[7]*cy + kk[8]*cz;
    float dep = fmaxf(uz, 1e-6f);
    float gx = 2.f*(ux/dep)*(1.f/448.f) - 1.f + ox;
    float gy = 2.f*(uy/dep)*(1.f/448.f) - 1.f + oy;
    float valid = (uz > 0.1f && gx >= -1.f && gx <= 1.f && gy >= -1.f && gy <= 1.f) ? 1.f : 0.f;
    float x = (gx+1.f)*16.f - 0.5f;
    float y = (gy+1.f)*16.f - 0.5f;
    float x0 = floorf(x), y0 = floorf(y);
    const float* fbase = fmT + (size_t)(b*4+v)*65536 + c;
    float sv = 0.f;
    #pragma unroll
    for(int t=0;t<4;++t){
      float xi = x0 + (float)(t&1), yi = y0 + (float)(t>>1);
      float wgt = (1.f - fabsf(x-xi))*(1.f - fabsf(y-yi));
      bool vt = (xi>=0.f && xi<32.f && yi>=0.f && yi<32.f);
      int xc = (int)fminf(fmaxf(xi,0.f),31.f);
      int yc = (int)fminf(fmaxf(yi,0.f),31.f);
      float smp = fbase[(yc*32+xc)*64];
      sv += vt ? wgt*smp : 0.f;
    }
    acc += valid * sv;
    vsum += valid;
  }
  vfeat[(size_t)bn*64 + c] = acc / (vsum + 1e-8f);
}

// ---------------- embed: g_emb / v_emb = relu(LN(x@W^T+b)) + bf16 copies ----------------
__global__ void k_embed(const float* __restrict__ gs, const float* __restrict__ vfeat,
   const float* __restrict__ pg_w, const float* __restrict__ pg_b,
   const float* __restrict__ pg_g, const float* __restrict__ pg_bb,
   const float* __restrict__ pv_w, const float* __restrict__ pv_b,
   const float* __restrict__ pv_g, const float* __restrict__ pv_bb,
   float* __restrict__ gemb, float* __restrict__ vemb,
   unsigned short* __restrict__ gembb, unsigned short* __restrict__ vembb){
  __shared__ float xs[64]; __shared__ float gsr[14]; __shared__ float red[2];
  int row = blockIdx.x; int d = threadIdx.x;
  if(d<14) gsr[d] = gs[(size_t)row*14+d];
  if(d<64) xs[d] = vfeat[(size_t)row*64+d];
  __syncthreads();
  float a = pg_b[d];
  #pragma unroll
  for(int j=0;j<14;++j) a += gsr[j]*pg_w[d*14+j];
  float mu = bsum<2>(a, red)*(1.f/128.f);
  float df = a-mu;
  float var = bsum<2>(df*df, red)*(1.f/128.f);
  float y = fmaxf(df*rsqrtf(var+1e-5f)*pg_g[d] + pg_bb[d], 0.f);
  gemb[(size_t)row*128+d] = y;
  gembb[(size_t)row*128+d] = bf16c(y);
  float av = pv_b[d];
  #pragma unroll
  for(int j=0;j<64;++j) av += xs[j]*pv_w[d*64+j];
  mu = bsum<2>(av, red)*(1.f/128.f);
  df = av-mu;
  var = bsum<2>(df*df, red)*(1.f/128.f);
  y = fmaxf(df*rsqrtf(var+1e-5f)*pv_g[d] + pv_bb[d], 0.f);
  vemb[(size_t)row*128+d] = y;
  vembb[(size_t)row*128+d] = bf16c(y);
}

// ---------------- fused QKV projection -> flash layout (bf16) ----------------
__global__ __launch_bounds__(256) void k_qkv(const unsigned short* __restrict__ GEb,
    const unsigned short* __restrict__ VEb, const unsigned short* __restrict__ WB,
    const float* __restrict__ ipb, unsigned* __restrict__ QKVu, float qsc){
  int mt = blockIdx.x, y = blockIdx.y;
  int m = y/6, j6 = y%6, kind = j6>>1, n0 = (j6&1)*64;
  const unsigned short* A = (kind==0) ? (m?VEb:GEb) : (m?GEb:VEb);
  const unsigned short* W = WB + m*49152 + kind*16384;
  const float* bias = ipb + m*384 + kind*128;
  unsigned* outb = QKVu + (size_t)m*1572864 + (size_t)kind*524288;
  float scale = (kind==0)? qsc : 1.f;
  int m0 = mt*64;
  int wid=threadIdx.x>>6, lane=threadIdx.x&63, lr=lane&15, lg=lane>>4;
  const unsigned short* ap = A + (size_t)(m0+wid*16+lr)*128 + lg*8;
  f32x4 acc[4] = {{0,0,0,0},{0,0,0,0},{0,0,0,0},{0,0,0,0}};
  #pragma unroll
  for(int ks=0; ks<128; ks+=32){
    FR af; af.v = *(const s16x8*)(ap + ks);
    #pragma unroll
    for(int nt=0; nt<4; ++nt){
      FR bf; bf.v = *(const s16x8*)(W + (size_t)(n0+nt*16+lr)*128 + ks + lg*8);
      acc[nt] = MF(af.v, bf.v, acc[nt]);
    }
  }
  __shared__ float xs[64][65];
  #pragma unroll
  for(int nt=0; nt<4; ++nt){
    float bv = bias[n0+nt*16+lr];
    #pragma unroll
    for(int r=0;r<4;++r) xs[wid*16+lg*4+r][nt*16+lr] = (acc[nt][r]+bv)*scale;
  }
  __syncthreads();
  if(kind<2){
    int i = threadIdx.x>>2, s = threadIdx.x&3;
    int gr = m0 + i, b = gr>>11, nn = gr&2047;
    int j0 = n0 + s*16, h = j0>>5, d0 = j0&31;
    unsigned w[8];
    #pragma unroll
    for(int p=0;p<8;++p) w[p] = pkbf(xs[i][s*16+2*p], xs[i][s*16+2*p+1]);
    unsigned* dst = outb + ((size_t)(b*4+h)*2048+nn)*16 + (d0>>1);
    uint4 u0; u0.x=w[0];u0.y=w[1];u0.z=w[2];u0.w=w[3];
    uint4 u1; u1.x=w[4];u1.y=w[5];u1.z=w[6];u1.w=w[7];
    *(uint4*)dst = u0; *(uint4*)(dst+4) = u1;
  } else {
    int c = threadIdx.x>>2, rs = threadIdx.x&3;
    int j = n0 + c, h = j>>5, d = j&31;
    int b = m0>>11, nn0 = m0&2047;
    unsigned w[8];
    #pragma unroll
    for(int p=0;p<8;++p) w[p] = pkbf(xs[rs*16+2*p][c], xs[rs*16+2*p+1][c]);
    unsigned* dst = outb + (size_t)(b*4+h)*32768 + (size_t)d*1024 + ((nn0+rs*16)>>1);
    uint4 u0; u0.x=w[0];u0.y=w[1];u0.z=w[2];u0.w=w[3];
    uint4 u1; u1.x=w[4];u1.y=w[5];u1.z=w[6];u1.w=w[7];
    *(uint4*)dst = u0; *(uint4*)(dst+4) = u1;
  }
}

// ---------------- MFMA bf16 flash attention v9: LDS staging, K+V XOR-swizzled ----------------
__global__ __launch_bounds__(256) void k_flash(const unsigned short* __restrict__ QKV,
    unsigned* __restrict__ OPARTw, float* __restrict__ LSUM){
  int qt = blockIdx.x, h = blockIdx.y, z = blockIdx.z;   // grid (32,4,16)
  int mb = z&7, split = z>>3;
  int m = mb>>2, b = mb&3;
  const unsigned short* base = QKV + (size_t)m*3145728;
  const unsigned short* qp = base + (size_t)(b*4+h)*65536;
  const unsigned short* kp = qp + 1048576;
  const unsigned short* vp = qp + 2097152;
  int tid=threadIdx.x, wid=tid>>6, lane=tid&63, lr=lane&15, lg=lane>>4;
  __shared__ unsigned short KT[2][2048];
  __shared__ unsigned short VT[2][2048];
  __shared__ unsigned Ps[4][16][33];
  int q0 = qt*64 + wid*16;
  int kbase = split*1024;
  FR qf; qf.v = *(const s16x8*)(qp + (size_t)(q0+lr)*32 + lg*8);
  const f32x4 zz = {0.f,0.f,0.f,0.f};
  f32x4 o0g = zz, o1g = zz;
  float lrun = 0.f;
  unsigned* prow = &Ps[wid][lr][0];
  int kr = wid*16 + (lane>>2);
  int kscol = (((lane&3)<<3) ^ (((lane>>3)&3)<<3));
  const unsigned short* ksrc0 = kp + (size_t)(kbase + kr)*32 + kscol;
  int vrow = wid*8 + (lane>>3);
  int vscol = 8*((lane&7) ^ (lane>>3));
  const unsigned short* vsrc0 = vp + (size_t)vrow*2048 + kbase + vscol;
  int kkey = ((lr>>1)&3)<<3;
  int ko = lr*32 + ((lg*8) ^ kkey);
  int sw = (lr&7)*8;
  int vo0 = lr*64 + ((lg*8) ^ sw);
  int vo2 = lr*64 + ((32+lg*8) ^ sw);
  gl_lds16(ksrc0, &KT[0][wid*512]);
  gl_lds16(vsrc0, &VT[0][wid*512]);
  __syncthreads();
  int buf = 0;
  for(int t=0; t<16; ++t){
    int tn = (t+1)&15;
    gl_lds16(ksrc0 + (size_t)tn*2048, &KT[buf^1][wid*512]);
    gl_lds16(vsrc0 + tn*64,           &VT[buf^1][wid*512]);
    const unsigned short* Ktb = &KT[buf][0];
    const unsigned short* Vtb = &VT[buf][0];
    FR k0,k1,k2,k3;
    k0.v = *(const s16x8*)(Ktb + ko);
    k1.v = *(const s16x8*)(Ktb +  512 + ko);
    k2.v = *(const s16x8*)(Ktb + 1024 + ko);
    k3.v = *(const s16x8*)(Ktb + 1536 + ko);
    f32x4 s0 = MF(k0.v, qf.v, zz);
    f32x4 s1 = MF(k1.v, qf.v, zz);
    f32x4 s2 = MF(k2.v, qf.v, zz);
    f32x4 s3 = MF(k3.v, qf.v, zz);
    float p0[4],p1[4],p2[4],p3[4]; float ps=0.f;
    #pragma unroll
    for(int r=0;r<4;++r){
      p0[r]=xexp2(s0[r]); p1[r]=xexp2(s1[r]);
      p2[r]=xexp2(s2[r]); p3[r]=xexp2(s3[r]);
      ps += p0[r]+p1[r]+p2[r]+p3[r];
    }
    lrun += ps;
    asm volatile("" ::: "memory");
    prow[   lg*2+0]=pkbf(p0[0],p0[1]); prow[   lg*2+1]=pkbf(p0[2],p0[3]);
    prow[ 8+lg*2+0]=pkbf(p1[0],p1[1]); prow[ 8+lg*2+1]=pkbf(p1[2],p1[3]);
    prow[16+lg*2+0]=pkbf(p2[0],p2[1]); prow[16+lg*2+1]=pkbf(p2[2],p2[3]);
    prow[24+lg*2+0]=pkbf(p3[0],p3[1]); prow[24+lg*2+1]=pkbf(p3[2],p3[3]);
    asm volatile("" ::: "memory");
    FR pf0, pf1;
    #pragma unroll
    for(int i=0;i<4;++i){ pf0.u[i]=prow[lg*4+i]; pf1.u[i]=prow[16+lg*4+i]; }
    FR v0,v1,v2,v3;
    v0.v = *(const s16x8*)(Vtb + vo0);
    v1.v = *(const s16x8*)(Vtb + 1024 + vo0);
    v2.v = *(const s16x8*)(Vtb + vo2);
    v3.v = *(const s16x8*)(Vtb + 1024 + vo2);
    o0g = MF(v0.v, pf0.v, o0g);
    o1g = MF(v1.v, pf0.v, o1g);
    o0g = MF(v2.v, pf1.v, o0g);
    o1g = MF(v3.v, pf1.v, o1g);
    __syncthreads();
    buf ^= 1;
  }
  lrun += __shfl_xor(lrun,16); lrun += __shfl_xor(lrun,32);
  unsigned w00=pkbf(o0g[0],o0g[1]), w01=pkbf(o0g[2],o0g[3]);
  unsigned w10=pkbf(o1g[0],o1g[1]), w11=pkbf(o1g[2],o1g[3]);
  unsigned* op = OPARTw + ((size_t)(split*2+m)*8192 + (size_t)(b*2048+q0+lr))*64 + h*16 + lg*2;
  op[0]=w00; op[1]=w01; op[8]=w10; op[9]=w11;
  if(lg==0) LSUM[((size_t)(split*2+m)*16 + b*4+h)*2048 + q0+lr] = lrun;
}

// ---------------- fused split-K merge + out-proj GEMM + bias + residual + LN ----------------
__global__ __launch_bounds__(256) void k_oproj(const unsigned* __restrict__ OPARTw,
    const float* __restrict__ LSUM,
    const unsigned short* __restrict__ WB, const float* __restrict__ ob,
    const float* __restrict__ GE, const float* __restrict__ VE,
    const float* __restrict__ dg, const float* __restrict__ db,
    float* __restrict__ CC, unsigned short* __restrict__ CCb){
  int mt = blockIdx.x, m = blockIdx.y;
  int m0 = mt*64;
  const unsigned short* W = WB + 98304 + m*16384;
  const float* bias = ob + m*128;
  const float* R = m ? VE : GE;
  const float* gamma = dg + m*128;
  const float* beta  = db + m*128;
  int wid=threadIdx.x>>6, lane=threadIdx.x&63, lr=lane&15, lg=lane>>4;
  int gr = m0 + wid*16 + lr;
  int b2 = gr>>11, nn = gr&2047;
  float invh[4];
  #pragma unroll
  for(int h=0;h<4;++h){
    float l0 = LSUM[((size_t)(m*16) + b2*4+h)*2048 + nn];
    float l1 = LSUM[((size_t)((2+m)*16) + b2*4+h)*2048 + nn];
    invh[h] = 1.f/(l0+l1);
  }
  const unsigned* a0 = OPARTw + ((size_t)m*8192 + gr)*64 + lg*4;
  const unsigned* a1 = OPARTw + ((size_t)(2+m)*8192 + gr)*64 + lg*4;
  f32x4 acc[8] = {};
  #pragma unroll
  for(int ks=0; ks<4; ++ks){
    uint4 u0 = *(const uint4*)(a0 + ks*16);
    uint4 u1 = *(const uint4*)(a1 + ks*16);
    float sc = invh[ks];
    FR af;
    af.u[0] = pkbf((ubf_lo(u0.x)+ubf_lo(u1.x))*sc, (ubf_hi(u0.x)+ubf_hi(u1.x))*sc);
    af.u[1] = pkbf((ubf_lo(u0.y)+ubf_lo(u1.y))*sc, (ubf_hi(u0.y)+ubf_hi(u1.y))*sc);
    af.u[2] = pkbf((ubf_lo(u0.z)+ubf_lo(u1.z))*sc, (ubf_hi(u0.z)+ubf_hi(u1.z))*sc);
    af.u[3] = pkbf((ubf_lo(u0.w)+ubf_lo(u1.w))*sc, (ubf_hi(u0.w)+ubf_hi(u1.w))*sc);
    #pragma unroll
    for(int nt=0; nt<8; ++nt){
      FR bf; bf.v = *(const s16x8*)(W + (size_t)(nt*16+lr)*128 + ks*32 + lg*8);
      acc[nt] = MF(af.v, bf.v, acc[nt]);
    }
  }
  __shared__ float xs[64][129];
  __shared__ float mus[64], rss[64];
  #pragma unroll
  for(int nt=0; nt<8; ++nt){
    float bv = bias[nt*16+lr];
    #pragma unroll
    for(int r=0;r<4;++r){
      int row = wid*16+lg*4+r;
      xs[row][nt*16+lr] = acc[nt][r] + bv + R[(size_t)(m0+row)*128 + nt*16+lr];
    }
  }
  __syncthreads();
  if(threadIdx.x < 64){
    int row = threadIdx.x;
    float s=0.f, s2=0.f;
    #pragma unroll 8
    for(int c=0;c<128;++c){ float x = xs[row][c]; s += x; s2 += x*x; }
    float mu = s*(1.f/128.f);
    float var = fmaxf(s2*(1.f/128.f) - mu*mu, 0.f);
    mus[row] = mu; rss[row] = rsqrtf(var + 1e-5f);
  }
  __syncthreads();
  int row = threadIdx.x>>2, cs = (threadIdx.x&3)*32;
  float mu = mus[row], rs = rss[row];
  size_t obase = (size_t)(m0+row)*256 + m*128;
  #pragma unroll 8
  for(int c=cs;c<cs+32;++c){
    float y = (xs[row][c]-mu)*rs*gamma[c] + beta[c];
    CC [obase + c] = y;
    CCb[obase + c] = bf16c(y);
  }
}

// ---------------- fused gate GEMM + sigmoid + mix -> FU ----------------
__global__ __launch_bounds__(256) void k_gatef(const unsigned short* __restrict__ CCb,
    const unsigned short* __restrict__ WB, const float* __restrict__ gate_b,
    const float* __restrict__ CC, float* __restrict__ FU){
  int mt = blockIdx.x;
  int m0 = mt*64;
  const unsigned short* W = WB + 131072;
  int wid=threadIdx.x>>6, lane=threadIdx.x&63, lr=lane&15, lg=lane>>4;
  const unsigned short* ap = CCb + (size_t)(m0+wid*16+lr)*256 + lg*8;
  f32x4 acc[8] = {};
  #pragma unroll
  for(int ks=0; ks<256; ks+=32){
    FR af; af.v = *(const s16x8*)(ap + ks);
    #pragma unroll
    for(int nt=0; nt<8; ++nt){
      FR bf; bf.v = *(const s16x8*)(W + (size_t)(nt*16+lr)*256 + ks + lg*8);
      acc[nt] = MF(af.v, bf.v, acc[nt]);
    }
  }
  #pragma unroll
  for(int nt=0; nt<8; ++nt){
    int col = nt*16+lr;
    float bv = gate_b[col];
    #pragma unroll
    for(int r=0;r<4;++r){
      int row = m0 + wid*16+lg*4+r;
      float gv = 1.f/(1.f+__expf(-(acc[nt][r]+bv)));
      FU[(size_t)row*128 + col] = CC[(size_t)row*256 + col]*gv
                                + CC[(size_t)row*256 + 128 + col]*(1.f-gv);
    }
  }
}

// ---------------- router ----------------
__global__ void k_rpart(const float* __restrict__ gemb, const float* __restrict__ vemb,
                        float* __restrict__ part){
  int blk = blockIdx.x;  // 64 = b(4) x ch(16), 128 rows each
  int b = blk>>4, ch = blk&15, t = threadIdx.x;
  const float* src = (t<128)? gemb : vemb;
  int d = t&127;
  float s=0.f;
  int n0 = ch*128;
  for(int n=0;n<128;++n) s += src[((size_t)(b*2048+n0+n))*128 + d];
  part[(size_t)blk*256 + t] = s;
}
__global__ void k_router(const float* __restrict__ part, const float* __restrict__ w1,
     const float* __restrict__ b1, const float* __restrict__ lg, const float* __restrict__ lb,
     const float* __restrict__ w2, const float* __restrict__ b2,
     float* __restrict__ rw, float* __restrict__ outrw){
  __shared__ float ri[256]; __shared__ float red[2];
  int b = blockIdx.x, t = threadIdx.x;  // 128 threads
  for(int j=t; j<256; j+=128){
    float s=0.f;
    for(int c=0;c<16;++c) s += part[(size_t)(b*16+c)*256 + j];
    ri[j] = s*(1.f/2048.f);
  }
  __syncthreads();
  float a = b1[t];
  for(int j=0;j<256;++j) a += ri[j]*w1[t*256+j];
  float mu = bsum<2>(a,red)*(1.f/128.f);
  float df = a-mu;
  float var = bsum<2>(df*df,red)*(1.f/128.f);
  float hv = fmaxf(df*rsqrtf(var+1e-5f)*lg[t]+lb[t], 0.f);
  float l0 = bsum<2>(hv*w2[t],red);
  float l1 = bsum<2>(hv*w2[128+t],red);
  float l2 = bsum<2>(hv*w2[256+t],red);
  if(t==0){
    l0+=b2[0]; l1+=b2[1]; l2+=b2[2];
    float mx = fmaxf(l0,fmaxf(l1,l2));
    float e0=__expf(l0-mx), e1=__expf(l1-mx), e2=__expf(l2-mx);
    float s=e0+e1+e2;
    rw[b*3+0]=e0/s; rw[b*3+1]=e1/s; rw[b*3+2]=e2/s;
    outrw[b*3+0]=e0/s; outrw[b*3+1]=e1/s; outrw[b*3+2]=e2/s;
  }
}

// ---------------- fused NetVLAD assign+aggregate (MFMA), per 64-row chunk ----------------
__global__ __launch_bounds__(256) void k_vlad1(
      const float* __restrict__ GE, const float* __restrict__ VE, const float* __restrict__ FU,
      const unsigned short* __restrict__ WBcw, const float* __restrict__ cbp,
      float* __restrict__ p0, float* __restrict__ p1, float* __restrict__ p2,
      float* __restrict__ asump){
  int ch = blockIdx.x, b = blockIdx.y, z = blockIdx.z;
  const float* feat = (z==0)?GE:((z==1)?VE:FU);
  const unsigned short* cwb = WBcw + z*8192;
  const float* cb = cbp + z*64;
  float* part = (z==0)?p0:((z==1)?p1:p2);
  float* asu = asump + z*8192;
  int t = threadIdx.x;
  __shared__ unsigned xnbu[64*36];
  __shared__ unsigned short xnbT[128*72];
  __shared__ unsigned abTu[64*36];
  int nbase = b*2048 + ch*64;
  {
    int r = t>>2, q = t&3;
    const float* frow = feat + (size_t)(nbase + r)*128 + q*32;
    float v[32]; float ssq = 0.f;
    #pragma unroll
    for(int i=0;i<8;++i){
      float4 f4 = *(const float4*)(frow + i*4);
      v[i*4+0]=f4.x; v[i*4+1]=f4.y; v[i*4+2]=f4.z; v[i*4+3]=f4.w;
      ssq += f4.x*f4.x+f4.y*f4.y+f4.z*f4.z+f4.w*f4.w;
    }
    ssq += __shfl_xor(ssq,1); ssq += __shfl_xor(ssq,2);
    float inv = 1.f/fmaxf(sqrtf(ssq),1e-12f);
    #pragma unroll
    for(int i=0;i<16;++i)
      xnbu[r*36 + q*8 + i] = pkbf(v[2*i]*inv, v[2*i+1]*inv);
    #pragma unroll
    for(int j=0;j<32;++j)
      xnbT[(q*32+j)*72 + r] = bf16c(v[j]*inv);
  }
  __syncthreads();
  int w = t>>6, lane = t&63, lr = lane&15, lg = lane>>4;
  {
    f32x4 acc[4] = {};
    #pragma unroll
    for(int ks=0; ks<4; ++ks){
      FR af; af.q = *(const uint4*)&xnbu[(w*16+lr)*36 + ks*16 + lg*4];
      #pragma unroll
      for(int nt=0; nt<4; ++nt){
        FR bf; bf.v = *(const s16x8*)(cwb + (size_t)(nt*16+lr)*128 + ks*32 + lg*8);
        acc[nt] = MF(af.v, bf.v, acc[nt]);
      }
    }
    float p[4][4]; float srow[4] = {0.f,0.f,0.f,0.f};
    #pragma unroll
    for(int nt=0;nt<4;++nt){
      float cbv = cb[nt*16+lr];
      #pragma unroll
      for(int rr=0;rr<4;++rr){
        p[nt][rr] = __expf(acc[nt][rr] + cbv);
        srow[rr] += p[nt][rr];
      }
    }
    #pragma unroll
    for(int rr=0;rr<4;++rr){
      float s = srow[rr];
      s += __shfl_xor(s,1); s += __shfl_xor(s,2); s += __shfl_xor(s,4); s += __shfl_xor(s,8);
      srow[rr] = 1.f/s;
    }
    #pragma unroll
    for(int nt=0;nt<4;++nt){
      int k = nt*16+lr;
      abTu[k*36 + w*8 + lg*2 + 0] = pkbf(p[nt][0]*srow[0], p[nt][1]*srow[1]);
      abTu[k*36 + w*8 + lg*2 + 1] = pkbf(p[nt][2]*srow[2], p[nt][3]*srow[3]);
    }
  }
  __syncthreads();
  {
    f32x4 acc[8] = {};
    #pragma unroll
    for(int ns=0; ns<2; ++ns){
      FR af; af.q = *(const uint4*)&abTu[(w*16+lr)*36 + ns*16 + lg*4];
      #pragma unroll
      for(int nt=0; nt<8; ++nt){
        FR bf; bf.v = *(const s16x8*)&xnbT[(nt*16+lr)*72 + ns*32 + lg*8];
        acc[nt] = MF(af.v, bf.v, acc[nt]);
      }
    }
    size_t pb = ((size_t)(b*32+ch)*64);
    #pragma unroll
    for(int nt=0; nt<8; ++nt){
      #pragma unroll
      for(int rr=0; rr<4; ++rr){
        int k = w*16+lg*4+rr;
        part[(pb + k)*128 + nt*16+lr] = acc[nt][rr];
      }
    }
  }
  if(t<64){
    float s = 0.f;
    #pragma unroll
    for(int i=0;i<32;++i){
      unsigned u = abTu[t*36+i];
      s += ubf_lo(u) + ubf_hi(u);
    }
    asu[((size_t)(b*32+ch))*64 + t] = s;
  }
}

// ---- vlad stage 2 (z-batched): reduce partials, subtract centers, l2n ----
__global__ void k_vagg2(
      const float* __restrict__ p0, const float* __restrict__ p1, const float* __restrict__ p2,
      const float* __restrict__ asump, const float* __restrict__ cent, float* __restrict__ vlad3){
  int k = blockIdx.x, b = blockIdx.y, z = blockIdx.z;   // grid (64,4,3), 128 thr
  const float* part = (z==0)?p0:((z==1)?p1:p2);
  const float* asu = asump + z*8192;
  const float* centp = cent + (size_t)z*8192;
  float* vlad = vlad3 + z*32768;
  int t = threadIdx.x;
  __shared__ float red[2];
  float v = 0.f;
  const float* pp = part + (((size_t)b*32)*64 + k)*128 + t;
  for(int ch=0; ch<32; ++ch) v += pp[(size_t)ch*8192];
  float as = 0.f;
  const float* ap = asu + (size_t)b*2048 + k;
  for(int ch=0; ch<32; ++ch) as += ap[(size_t)ch*64];
  v -= as * centp[(size_t)k*128 + t];
  float ssq = bsum<2>(v*v, red);
  float inv = 1.f/fmaxf(sqrtf(ssq),1e-12f);
  vlad[((size_t)b*64+k)*128+t] = v*inv;
}

// ---- descriptor GEMV (z-batched, LDS-staged) ----
__global__ __launch_bounds__(256) void k_desc(const float* __restrict__ vlad3,
      const float* __restrict__ bnw, const float* __restrict__ bnb, float* __restrict__ DT){
  int jg = blockIdx.x, b = blockIdx.y, z = blockIdx.z;   // grid (64,4,3)
  const float* vlad = vlad3 + z*32768;
  const float* bw = bnw + (size_t)z*2097152;
  const float* bb = bnb + z*256;
  float* dtmp = DT + z*1024;
  int t = threadIdx.x;
  __shared__ float fl[8192]; __shared__ float red[4];
  const float4* src = (const float4*)(vlad + (size_t)b*8192);
  float4* fl4 = (float4*)fl;
  float ssq = 0.f;
  #pragma unroll
  for(int i=0;i<8;++i){
    float4 vv = src[t + i*256]; fl4[t+i*256]=vv;
    ssq += vv.x*vv.x+vv.y*vv.y+vv.z*vv.z+vv.w*vv.w;
  }
  ssq = bsum<4>(ssq, red);
  float inv = 1.f/fmaxf(sqrtf(ssq),1e-12f);
  for(int jj=0;jj<4;++jj){
    int j = jg*4 + jj;
    const float4* wp = (const float4*)(bw + (size_t)j*8192);
    float s = 0.f;
    #pragma unroll
    for(int i=0;i<8;++i){
      int f = t + i*256;
      float4 w4 = wp[f]; float4 x4 = fl4[f];
      s += w4.x*x4.x+w4.y*x4.y+w4.z*x4.z+w4.w*x4.w;
    }
    s = bsum<4>(s, red);
    if(t==0) dtmp[(size_t)b*256 + j] = s*inv + bb[j];
  }
}

// ---------------- final ----------------
__global__ void k_final(const float* __restrict__ dtmp, const float* __restrict__ lg,
      const float* __restrict__ lb, const float* __restrict__ rw, float* __restrict__ outp){
  __shared__ float red[4];
  int b = blockIdx.x, t = threadIdx.x;  // 256
  float acc = 0.f;
  for(int i=0;i<3;++i){
    float x = dtmp[(size_t)(i*4+b)*256 + t];
    float mu = bsum<4>(x,red)*(1.f/256.f);
    float df = x-mu;
    float var = bsum<4>(df*df,red)*(1.f/256.f);
    float y = df*rsqrtf(var+1e-5f)*lg[i*256+t]+lb[i*256+t];
    float n2 = bsum<4>(y*y,red);
    y = y / fmaxf(sqrtf(n2),1e-12f);
    acc += rw[b*3+i]*y;
  }
  float n2 = bsum<4>(acc*acc,red);
  outp[(size_t)b*256+t] = acc/fmaxf(sqrtf(n2),1e-12f);
}

// ---------------- host ----------------
extern "C" void kernel_launch(void* const* d_in, const int* in_sizes, int n_in,
                              void* d_out, int out_size, void* d_ws, size_t ws_size,
                              hipStream_t stream){
  const float* gaussians=(const float*)d_in[0];
  const float* visual=(const float*)d_in[1];
  const float* extr=(const float*)d_in[2];
  const float* intr=(const float*)d_in[3];
  const float* offs=(const float*)d_in[4];
  const float* pg_w=(const float*)d_in[5];
  const float* pg_b=(const float*)d_in[6];
  const float* pg_g=(const float*)d_in[7];
  const float* pg_bb=(const float*)d_in[8];
  const float* pv_w=(const float*)d_in[9];
  const float* pv_b=(const float*)d_in[10];
  const float* pv_g=(const float*)d_in[11];
  const float* pv_bb=(const float*)d_in[12];
  const float* ipw=(const float*)d_in[13];
  const float* ipb=(const float*)d_in[14];
  const float* ow=(const float*)d_in[15];
  const float* ob=(const float*)d_in[16];
  const float* dg=(const float*)d_in[17];
  const float* db=(const float*)d_in[18];
  const float* gate_w=(const float*)d_in[19];
  const float* gate_b=(const float*)d_in[20];
  const float* rw1=(const float*)d_in[21];
  const float* rb1=(const float*)d_in[22];
  const float* rlg=(const float*)d_in[23];
  const float* rlb=(const float*)d_in[24];
  const float* rw2=(const float*)d_in[25];
  const float* rb2=(const float*)d_in[26];
  const float* cent=(const float*)d_in[27];
  const float* cw=(const float*)d_in[28];
  const float* cb=(const float*)d_in[29];
  const float* bnw=(const float*)d_in[30];
  const float* bnb=(const float*)d_in[31];
  const float* blg=(const float*)d_in[32];
  const float* blb=(const float*)d_in[33];
  float* outp=(float*)d_out;
  float* ws=(float*)d_ws;

  // ws map (floats), high-water ~11.38M floats (~45.5MB); 48.2MB proven usable (r2)
  float* FMT = ws + 0;               // 1M (phase1)
  float* VF  = ws + 1048576;         // 0.5M
  float* GE  = ws + 1572864;         // 1M (live through vlad1)
  float* VE  = ws + 2621440;         // 1M (live through vlad1)
  unsigned short* GEb = (unsigned short*)(ws + 3670016);   // dead post-qkv -> PART0
  unsigned short* VEb = (unsigned short*)(ws + 4194304);
  unsigned* QKVu = (unsigned*)(ws + 4718592);              // 3M; dead post-flash
  float* CC  = ws + 4718592;         // 2M (post-flash)
  unsigned short* CCb = (unsigned short*)(ws + 6815744);   // 1M floats worth (post-flash)
  unsigned* OPARTw = (unsigned*)(ws + 7864320);            // 2M words; dead post-oproj
  float* FU  = ws + 8912896;         // 1M (written by gatef, after OPART dead)
  unsigned short* WB = (unsigned short*)(ws + 9961472);    // 94208 floats worth
  float* RP  = ws + 10055680;        // 16384
  float* DT  = ws + 10072064;        // 3072
  float* RW  = ws + 10075136;        // 16
  float* VLAD3 = ws + 10075152;      // 98304
  float* PART2 = ws + 10173456;      // 1M
  float* ASUMP3 = ws + 11222032;     // 24576
  float* LSUM  = ws + 11246608;      // 131072 (flash phase)
  float* PART0 = ws + 3670016;       // over GEb/VEb (dead post-qkv)
  float* PART1 = ws + 7864320;       // over OPART (dead post-oproj)
  const unsigned short* QKVh = (const unsigned short*)QKVu;

  k_prep<<<992,256,0,stream>>>(visual, FMT, ipw, ow, gate_w, cw, WB);
  k_proj<<<2048,256,0,stream>>>(gaussians, FMT, extr, intr, offs, VF);
  k_embed<<<8192,128,0,stream>>>(gaussians, VF, pg_w,pg_b,pg_g,pg_bb,
                                 pv_w,pv_b,pv_g,pv_bb, GE, VE, GEb, VEb);
  k_rpart<<<64,256,0,stream>>>(GE, VE, RP);
  k_router<<<4,128,0,stream>>>(RP, rw1,rb1,rlg,rlb,rw2,rb2, RW, outp+1024);

  const float qsc = 1.4426950408889634f * 0.17677669529663687f;  // log2e/sqrt(32)
  k_qkv<<<dim3(128,12),256,0,stream>>>(GEb, VEb, WB, ipb, QKVu, qsc);
  k_flash<<<dim3(32,4,16),256,0,stream>>>(QKVh, OPARTw, LSUM);
  k_oproj<<<dim3(128,2),256,0,stream>>>(OPARTw, LSUM, WB, ob, GE, VE, dg, db, CC, CCb);
  k_gatef<<<128,256,0,stream>>>(CCb, WB, gate_b, CC, FU);
  k_vlad1<<<dim3(32,4,3),256,0,stream>>>(GE, VE, FU, WB+163840, cb,
                                         PART0, PART1, PART2, ASUMP3);
  k_vagg2<<<dim3(64,4,3),128,0,stream>>>(PART0,PART1,PART2, ASUMP3, cent, VLAD3);
  k_desc<<<dim3(64,4,3),256,0,stream>>>(VLAD3, bnw, bnb, DT);
  k_final<<<4,256,0,stream>>>(DT, blg, blb, RW, outp);
}